// Round 8
// baseline (264.961 us; speedup 1.0000x reference)
//
#include <hip/hip_runtime.h>
#include <hip/hip_bf16.h>
#include <math.h>

// Problem dims (fixed by the reference)
#define NB 8
#define NC 512
#define NN 2048

typedef unsigned short u16;
typedef __attribute__((ext_vector_type(8))) short short8;
typedef __attribute__((ext_vector_type(4))) float f32x4;

__device__ __forceinline__ float bf16_to_f32(u16 v) {
  union { unsigned int u; float f; } c; c.u = ((unsigned int)v) << 16; return c.f;
}
__device__ __forceinline__ u16 f32_to_bf16(float f) {
  __hip_bfloat16 h = __float2bfloat16(f);   // RNE
  union { __hip_bfloat16 h; u16 u; } c; c.h = h; return c.u;
}
__device__ __forceinline__ void split2(float v, unsigned short& hi, unsigned short& lo) {
  hi = f32_to_bf16(v);
  lo = f32_to_bf16(v - bf16_to_f32(hi));
}

__device__ __forceinline__ void gl_lds16(const void* g, void* l) {
  __builtin_amdgcn_global_load_lds(
      (const __attribute__((address_space(1))) unsigned int*)g,
      (__attribute__((address_space(3))) unsigned int*)l, 16, 0, 0);
}

// stage 128 rows x 32 u16 (64 B/row, 8 KB) into LDS via global_load_lds w=16.
// (256-thread kernels: proj)
__device__ __forceinline__ void stage128x32(const u16* __restrict__ src, size_t row_base,
                                            int selems, int k0, u16* lds, int tid) {
#pragma unroll
  for (int s = 0; s < 2; ++s) {
    int flat = s * 4096 + tid * 16;   // byte offset within tile
    int row = flat >> 6;
    int kb  = flat & 63;
    const char* g = (const char*)(src + (row_base + row) * (size_t)selems + k0) + kb;
    u16* l = lds + s * 2048 + (tid & ~63) * 8;  // wave-uniform base; HW adds lane*16
    gl_lds16(g, l);
  }
}

// ---------------------------------------------------------------------------
// W split: [Wq;Wk;Wv] fp32 -> Whi/Wlo bf16 [640][512]
// ---------------------------------------------------------------------------
__global__ __launch_bounds__(256)
void wsplit_kernel(const float* __restrict__ Wq, const float* __restrict__ Wk,
                   const float* __restrict__ Wv, u16* __restrict__ Whi,
                   u16* __restrict__ Wlo) {
  int idx = (blockIdx.x * 256 + threadIdx.x) * 4;   // 640*512 total, exact grid
  int r = idx >> 9, c = idx & 511;
  const float* src;
  if (r < 64)       src = Wq + (size_t)r * NC + c;
  else if (r < 128) src = Wk + (size_t)(r - 64) * NC + c;
  else              src = Wv + (size_t)(r - 128) * NC + c;
  float4 v = *(const float4*)src;
  ushort4 hi, lo;
  split2(v.x, hi.x, lo.x); split2(v.y, hi.y, lo.y);
  split2(v.z, hi.z, lo.z); split2(v.w, hi.w, lo.w);
  *(ushort4*)&Whi[idx] = hi;
  *(ushort4*)&Wlo[idx] = lo;
}

// ---------------------------------------------------------------------------
// x transpose + split: x[b][c][n] fp32 -> xThi/xTlo[b][n][c] bf16
// ---------------------------------------------------------------------------
__global__ __launch_bounds__(256)
void xsplit_kernel(const float* __restrict__ x, u16* __restrict__ xThi,
                   u16* __restrict__ xTlo) {
  const int b = blockIdx.z, c0 = blockIdx.y * 64, n0 = blockIdx.x * 64;
  __shared__ float t[64][65];
  const int tid = threadIdx.x, tx = tid & 15, ty = tid >> 4;
#pragma unroll
  for (int r = 0; r < 4; ++r) {
    int c = r * 16 + ty;
    float4 v = *(const float4*)&x[((size_t)b * NC + c0 + c) * NN + n0 + tx * 4];
    t[c][tx * 4 + 0] = v.x; t[c][tx * 4 + 1] = v.y;
    t[c][tx * 4 + 2] = v.z; t[c][tx * 4 + 3] = v.w;
  }
  __syncthreads();
#pragma unroll
  for (int r = 0; r < 4; ++r) {
    int n = r * 16 + ty;
    ushort4 hi, lo;
    split2(t[tx * 4 + 0][n], hi.x, lo.x);
    split2(t[tx * 4 + 1][n], hi.y, lo.y);
    split2(t[tx * 4 + 2][n], hi.z, lo.z);
    split2(t[tx * 4 + 3][n], hi.w, lo.w);
    size_t off = ((size_t)b * NN + n0 + n) * NC + c0 + tx * 4;
    *(ushort4*)&xThi[off] = hi;
    *(ushort4*)&xTlo[off] = lo;
  }
}

// ---------------------------------------------------------------------------
// Projections, MFMA.  Double-buffered LDS + SINGLE barrier per K-step.
//   blockIdx.y==0: rows 0..127 = [f;g] -> fgT[b][n][128] split bf16 (3-term)
//   blockIdx.y>=1: rows 128..639 = h   -> h[b][c][n] plain bf16 (single-term)
// ---------------------------------------------------------------------------
__global__ __launch_bounds__(256)
void proj_mfma_kernel(const u16* __restrict__ xThi, const u16* __restrict__ xTlo,
                      const u16* __restrict__ Whi, const u16* __restrict__ Wlo,
                      u16* __restrict__ fgThi, u16* __restrict__ fgTlo,
                      u16* __restrict__ hw) {
  const int b  = blockIdx.z;
  const int n0 = blockIdx.x * 128;
  const int r0 = blockIdx.y * 128;
  const bool fg = (r0 == 0);

  __shared__ u16 Wh[2][128 * 32], Wl[2][128 * 32], Xh[2][128 * 32], Xl[2][128 * 32];

  const int tid = threadIdx.x, wave = tid >> 6, lane = tid & 63;
  const int quad = lane >> 4, l16 = lane & 15;
  const int wa = (wave >> 1) * 64, wb = (wave & 1) * 64;
  const size_t xrow = (size_t)b * NN + n0;

  f32x4 acc[4][4];
#pragma unroll
  for (int i = 0; i < 4; ++i)
#pragma unroll
    for (int j = 0; j < 4; ++j) acc[i][j] = (f32x4){0.f, 0.f, 0.f, 0.f};

  // prologue: stage k=0 into buf 0
  stage128x32(Whi, r0, NC, 0, Wh[0], tid);
  stage128x32(xThi, xrow, NC, 0, Xh[0], tid);
  if (fg) {
    stage128x32(Wlo, r0, NC, 0, Wl[0], tid);
    stage128x32(xTlo, xrow, NC, 0, Xl[0], tid);
  }

  const int KIT = NC / 32;   // 16
  for (int ki = 0; ki < KIT; ++ki) {
    __syncthreads();   // drains vmcnt -> buf[ki&1] ready; lgkm -> prior reads done
    if (ki + 1 < KIT) {
      const int nb = (ki + 1) & 1, k1 = (ki + 1) * 32;
      stage128x32(Whi, r0, NC, k1, Wh[nb], tid);
      stage128x32(xThi, xrow, NC, k1, Xh[nb], tid);
      if (fg) {
        stage128x32(Wlo, r0, NC, k1, Wl[nb], tid);
        stage128x32(xTlo, xrow, NC, k1, Xl[nb], tid);
      }
    }
    const int cur = ki & 1;

    if (fg) {
      short8 ah[4], al[4], bh[4], bl[4];
#pragma unroll
      for (int i = 0; i < 4; ++i) {
        ah[i] = *(short8*)&Wh[cur][(wa + i * 16 + l16) * 32 + quad * 8];
        al[i] = *(short8*)&Wl[cur][(wa + i * 16 + l16) * 32 + quad * 8];
      }
#pragma unroll
      for (int j = 0; j < 4; ++j) {
        bh[j] = *(short8*)&Xh[cur][(wb + j * 16 + l16) * 32 + quad * 8];
        bl[j] = *(short8*)&Xl[cur][(wb + j * 16 + l16) * 32 + quad * 8];
      }
#pragma unroll
      for (int i = 0; i < 4; ++i)
#pragma unroll
        for (int j = 0; j < 4; ++j) {
          acc[i][j] = __builtin_amdgcn_mfma_f32_16x16x32_bf16(ah[i], bh[j], acc[i][j], 0, 0, 0);
          acc[i][j] = __builtin_amdgcn_mfma_f32_16x16x32_bf16(ah[i], bl[j], acc[i][j], 0, 0, 0);
          acc[i][j] = __builtin_amdgcn_mfma_f32_16x16x32_bf16(al[i], bh[j], acc[i][j], 0, 0, 0);
        }
    } else {
      short8 ah[4], bh[4];
#pragma unroll
      for (int i = 0; i < 4; ++i)
        ah[i] = *(short8*)&Xh[cur][(wa + i * 16 + l16) * 32 + quad * 8];
#pragma unroll
      for (int j = 0; j < 4; ++j)
        bh[j] = *(short8*)&Wh[cur][(wb + j * 16 + l16) * 32 + quad * 8];
#pragma unroll
      for (int i = 0; i < 4; ++i)
#pragma unroll
        for (int j = 0; j < 4; ++j)
          acc[i][j] = __builtin_amdgcn_mfma_f32_16x16x32_bf16(ah[i], bh[j], acc[i][j], 0, 0, 0);
    }
  }

  if (fg) {
#pragma unroll
    for (int i = 0; i < 4; ++i)
#pragma unroll
      for (int j = 0; j < 4; ++j) {
        int rb = wa + i * 16 + quad * 4;
        int n  = n0 + wb + j * 16 + l16;
        ushort4 hi, lo;
        split2(acc[i][j][0], hi.x, lo.x); split2(acc[i][j][1], hi.y, lo.y);
        split2(acc[i][j][2], hi.z, lo.z); split2(acc[i][j][3], hi.w, lo.w);
        size_t off = ((size_t)b * NN + n) * 128 + rb;
        *(ushort4*)&fgThi[off] = hi;
        *(ushort4*)&fgTlo[off] = lo;
      }
  } else {
#pragma unroll
    for (int i = 0; i < 4; ++i)
#pragma unroll
      for (int j = 0; j < 4; ++j) {
        int nb = n0 + wa + i * 16 + quad * 4;
        int c  = r0 - 128 + wb + j * 16 + l16;
        ushort4 hi;
        hi.x = f32_to_bf16(acc[i][j][0]); hi.y = f32_to_bf16(acc[i][j][1]);
        hi.z = f32_to_bf16(acc[i][j][2]); hi.w = f32_to_bf16(acc[i][j][3]);
        *(ushort4*)&hw[((size_t)b * NC + c) * NN + nb] = hi;
      }
  }
}

// ---------------------------------------------------------------------------
// Fused scores+softmax+PV+epilogue (flash-style; E never materialized).
// R8 = R7's H-in-registers + R6's 2-blocks/CU + zero S duplication:
//   m-tile 32, c-tile 512 (unsplit) -> 512 blocks = 8b x 64mt, 2 blocks/CU
//   = 4 waves/SIMD.  LDS ~36 KB: F dbuf (32K) + P [32][64] (4K) + Dn.
//   Per wave: S = 6 MFMA (n16 x m16, 3-term, g in regs), exp x4,
//   PV = 16 MFMA (c64 x m32) with H gathered global->reg (hreg[8]) at iter
//   top — L2 latency hides under S+exp AND under the co-resident block
//   (R7's failure was 1 block/CU: nothing filled the barrier/gather gaps).
//   Mid barrier lgkm-only (P visibility); trailing __syncthreads drains
//   the F[t+1] global_load_lds.  b = blockIdx&7 pins each b to one XCD L2.
// ---------------------------------------------------------------------------
__global__ __launch_bounds__(512, 4)
void attn_out_kernel(const u16* __restrict__ fgThi, const u16* __restrict__ fgTlo,
                     const u16* __restrict__ hw, const float* __restrict__ x,
                     const float* __restrict__ gamma, float* __restrict__ out) {
  const int s = blockIdx.x;            // 0..511
  const int b = s & 7;                 // XCD pin: all mt-blocks of b share L2
  const int mt = s >> 3;               // 0..63
  const int m0 = mt * 32;

  __shared__ u16 Fh[2][64 * 64], Fl[2][64 * 64];   // f [n][ch] 8 KB each
  __shared__ u16 Ps[32 * 64];                      // P [m][n] 4 KB
  __shared__ float Dn[32];

  const int tid = threadIdx.x, wave = tid >> 6, lane = tid & 63;
  const int quad = lane >> 4, l16 = lane & 15;
  const int ws_n = (wave >> 1) * 16, ws_m = (wave & 1) * 16;   // S partition
  const int wv_c = wave * 64;                                  // PV partition

  const size_t frow = (size_t)b * NN;
  const size_t hbase = (size_t)b * NC;

  // g fragments -> registers (iter-invariant; cols 64..127 of fgT)
  short8 gh[2], gl[2];
#pragma unroll
  for (int k = 0; k < 2; ++k) {
    size_t o = (frow + m0 + ws_m + l16) * 128 + 64 + k * 32 + quad * 8;
    gh[k] = *(const short8*)&fgThi[o];
    gl[k] = *(const short8*)&fgTlo[o];
  }

  // prologue: stage F[0]
  {
    int flat = tid * 16;
    int row = flat >> 7, chunk = (flat >> 4) & 7;
    int kb = ((chunk ^ (row & 7)) << 4);
    gl_lds16((const char*)(fgThi + (frow + row) * 128) + kb, Fh[0] + (tid & ~63) * 8);
    gl_lds16((const char*)(fgTlo + (frow + row) * 128) + kb, Fl[0] + (tid & ~63) * 8);
  }
  __syncthreads();   // F[0] landed

  float dsum = 0.f;
  f32x4 ao[4][2];
#pragma unroll
  for (int i = 0; i < 4; ++i)
#pragma unroll
    for (int j = 0; j < 2; ++j) ao[i][j] = (f32x4){0.f, 0.f, 0.f, 0.f};

  const int NT = NN / 64;   // 32
  for (int it = 0; it < NT; ++it) {
    const int cur = it & 1;
    const int n1 = it * 64;

    // H fragments for PV[it]: global -> registers (no LDS round-trip).
    short8 hreg[8];
#pragma unroll
    for (int i = 0; i < 4; ++i)
#pragma unroll
      for (int k = 0; k < 2; ++k)
        hreg[i * 2 + k] = *(const short8*)&hw[
            (hbase + wv_c + i * 16 + l16) * NN + n1 + (k * 4 + quad) * 8];

    // issue F[it+1] (global_load_lds; drained by trailing __syncthreads)
    if (it + 1 < NT) {
      const int nf = (it + 1) * 64;
      int flat = tid * 16;
      int row = flat >> 7, chunk = (flat >> 4) & 7;
      int kb = ((chunk ^ (row & 7)) << 4);
      gl_lds16((const char*)(fgThi + (frow + nf + row) * 128) + kb,
               Fh[cur ^ 1] + (tid & ~63) * 8);
      gl_lds16((const char*)(fgTlo + (frow + nf + row) * 128) + kb,
               Fl[cur ^ 1] + (tid & ~63) * 8);
    }

    // ---- S[it]: S[n16 x m16] per wave, 3-term split, g from registers ----
    f32x4 as = (f32x4){0.f, 0.f, 0.f, 0.f};
#pragma unroll
    for (int k = 0; k < 2; ++k) {
      int rr = ws_n + l16;
      int ci = (((k * 4 + quad) ^ (rr & 7)) << 3);
      short8 fh = *(short8*)&Fh[cur][rr * 64 + ci];
      short8 fl = *(short8*)&Fl[cur][rr * 64 + ci];
      as = __builtin_amdgcn_mfma_f32_16x16x32_bf16(fh, gh[k], as, 0, 0, 0);
      as = __builtin_amdgcn_mfma_f32_16x16x32_bf16(fh, gl[k], as, 0, 0, 0);
      as = __builtin_amdgcn_mfma_f32_16x16x32_bf16(fl, gh[k], as, 0, 0, 0);
    }

    // exp + P write (bf16, swizzled [m][n]) + denom partials
    {
      int m = ws_m + l16;
      float e0 = __expf(as[0]);
      float e1 = __expf(as[1]);
      float e2 = __expf(as[2]);
      float e3 = __expf(as[3]);
      dsum += (e0 + e1) + (e2 + e3);
      ushort4 pk;
      pk.x = f32_to_bf16(e0); pk.y = f32_to_bf16(e1);
      pk.z = f32_to_bf16(e2); pk.w = f32_to_bf16(e3);
      int nb = ws_n * 2 + quad * 8;                 // byte offset in row
      int chunk = nb >> 4;
      int off = (nb & 15) >> 1;                     // u16 offset in chunk
      *(ushort4*)&Ps[m * 64 + ((chunk ^ (m & 7)) << 3) + off] = pk;
    }

    // mid barrier: P visible (lgkm only; hreg/F vmem stays in flight — the
    // compiler waits the hreg loads right before their PV use)
    asm volatile("s_waitcnt lgkmcnt(0)" ::: "memory");
    __builtin_amdgcn_s_barrier();

    // ---- PV[it]: ao[c512 x m32] += h x P, H from registers ----
#pragma unroll
    for (int k = 0; k < 2; ++k) {
      short8 pb[2];
#pragma unroll
      for (int j = 0; j < 2; ++j) {
        int rm = j * 16 + l16;
        pb[j] = *(short8*)&Ps[rm * 64 + ((((k * 4 + quad)) ^ (rm & 7)) << 3)];
      }
#pragma unroll
      for (int i = 0; i < 4; ++i)
#pragma unroll
        for (int j = 0; j < 2; ++j)
          ao[i][j] = __builtin_amdgcn_mfma_f32_16x16x32_bf16(hreg[i * 2 + k], pb[j], ao[i][j], 0, 0, 0);
    }

    // iter-end: PV reads done -> P free; drains F[it+1] for next S
    __syncthreads();
  }

  // ---- epilogue: denom reduce (deterministic, in-block) ----
  dsum += __shfl_xor(dsum, 16);
  dsum += __shfl_xor(dsum, 32);
  if (tid < 32) Dn[tid] = 0.f;
  __syncthreads();
  if (quad == 0) atomicAdd(&Dn[ws_m + l16], dsum);
  __syncthreads();

  const float g = gamma[0];
  float invd[2];
#pragma unroll
  for (int j = 0; j < 2; ++j)
    invd[j] = g / Dn[j * 16 + l16];

#pragma unroll
  for (int i = 0; i < 4; ++i) {
#pragma unroll
    for (int j = 0; j < 2; ++j) {
      const int c = wv_c + i * 16 + quad * 4;
      const int m = m0 + j * 16 + l16;
#pragma unroll
      for (int r = 0; r < 4; ++r) {
        size_t off = ((size_t)b * NC + c + r) * NN + m;
        out[off] = fmaf(invd[j], ao[i][j][r], x[off]);
      }
    }
  }
}

// ---------------------------------------------------------------------------
extern "C" void kernel_launch(void* const* d_in, const int* in_sizes, int n_in,
                              void* d_out, int out_size, void* d_ws, size_t ws_size,
                              hipStream_t stream) {
  const float* x     = (const float*)d_in[0];
  const float* Wq    = (const float*)d_in[1];
  const float* Wk    = (const float*)d_in[2];
  const float* Wv    = (const float*)d_in[3];
  const float* gamma = (const float*)d_in[4];
  float* out = (float*)d_out;

  // Workspace:
  //   [0          ) xThi bf16 [8][2048][512]   16,777,216
  //   [16,777,216 ) xTlo                        16,777,216
  //   [33,554,432 ) Whi  bf16 [640][512]           655,360
  //   [34,209,792 ) Wlo                            655,360
  //   [67,108,864 ) fgThi bf16 [8][2048][128]    4,194,304
  //   [71,303,168 ) fgTlo                        4,194,304
  //   [75,497,472 ) hw    bf16 [8][512][2048]   16,777,216
  char* ws = (char*)d_ws;
  u16*   xThi  = (u16*)ws;
  u16*   xTlo  = (u16*)(ws + 16777216);
  u16*   Whi   = (u16*)(ws + 33554432);
  u16*   Wlo   = (u16*)(ws + 34209792);
  u16*   fgThi = (u16*)(ws + 67108864);
  u16*   fgTlo = (u16*)(ws + 71303168);
  u16*   hw    = (u16*)(ws + 75497472);

  wsplit_kernel<<<dim3(320), 256, 0, stream>>>(Wq, Wk, Wv, Whi, Wlo);
  xsplit_kernel<<<dim3(NN / 64, NC / 64, NB), 256, 0, stream>>>(x, xThi, xTlo);
  proj_mfma_kernel<<<dim3(NN / 128, 5, NB), 256, 0, stream>>>(
      xThi, xTlo, Whi, Wlo, fgThi, fgTlo, hw);
  attn_out_kernel<<<dim3(512), 512, 0, stream>>>(fgThi, fgTlo, hw, x, gamma, out);
}

// Round 10
// 214.030 us; speedup vs baseline: 1.2380x; 1.2380x over previous
//
#include <hip/hip_runtime.h>
#include <hip/hip_bf16.h>
#include <math.h>

// Problem dims (fixed by the reference)
#define NB 8
#define NC 512
#define NN 2048

typedef unsigned short u16;
typedef __attribute__((ext_vector_type(8))) short short8;
typedef __attribute__((ext_vector_type(4))) float f32x4;

__device__ __forceinline__ float bf16_to_f32(u16 v) {
  union { unsigned int u; float f; } c; c.u = ((unsigned int)v) << 16; return c.f;
}
__device__ __forceinline__ u16 f32_to_bf16(float f) {
  __hip_bfloat16 h = __float2bfloat16(f);   // RNE
  union { __hip_bfloat16 h; u16 u; } c; c.h = h; return c.u;
}
__device__ __forceinline__ void split2(float v, unsigned short& hi, unsigned short& lo) {
  hi = f32_to_bf16(v);
  lo = f32_to_bf16(v - bf16_to_f32(hi));
}

__device__ __forceinline__ void gl_lds16(const void* g, void* l) {
  __builtin_amdgcn_global_load_lds(
      (const __attribute__((address_space(1))) unsigned int*)g,
      (__attribute__((address_space(3))) unsigned int*)l, 16, 0, 0);
}

// stage 128 rows x 32 u16 (64 B/row, 8 KB) into LDS via global_load_lds w=16.
__device__ __forceinline__ void stage128x32(const u16* __restrict__ src, size_t row_base,
                                            int selems, int k0, u16* lds, int tid) {
#pragma unroll
  for (int s = 0; s < 2; ++s) {
    int flat = s * 4096 + tid * 16;   // byte offset within tile
    int row = flat >> 6;
    int kb  = flat & 63;
    const char* g = (const char*)(src + (row_base + row) * (size_t)selems + k0) + kb;
    u16* l = lds + s * 2048 + (tid & ~63) * 8;  // wave-uniform base; HW adds lane*16
    gl_lds16(g, l);
  }
}

// ---------------------------------------------------------------------------
// W split: [Wq;Wk;Wv] fp32 -> Whi/Wlo bf16 [640][512]
// ---------------------------------------------------------------------------
__global__ __launch_bounds__(256)
void wsplit_kernel(const float* __restrict__ Wq, const float* __restrict__ Wk,
                   const float* __restrict__ Wv, u16* __restrict__ Whi,
                   u16* __restrict__ Wlo) {
  int idx = (blockIdx.x * 256 + threadIdx.x) * 4;   // 640*512 total, exact grid
  int r = idx >> 9, c = idx & 511;
  const float* src;
  if (r < 64)       src = Wq + (size_t)r * NC + c;
  else if (r < 128) src = Wk + (size_t)(r - 64) * NC + c;
  else              src = Wv + (size_t)(r - 128) * NC + c;
  float4 v = *(const float4*)src;
  ushort4 hi, lo;
  split2(v.x, hi.x, lo.x); split2(v.y, hi.y, lo.y);
  split2(v.z, hi.z, lo.z); split2(v.w, hi.w, lo.w);
  *(ushort4*)&Whi[idx] = hi;
  *(ushort4*)&Wlo[idx] = lo;
}

// ---------------------------------------------------------------------------
// Projections, MFMA.  R9: x transpose+split FUSED into staging (xsplit
// kernel deleted).  Per K-step the X tile [128 n][32 c] is read straight
// from x fp32 (coalesced f32x4 along n), converted in-register, and
// ds_written transposed into the double-buffered LDS tile (T14 write-late:
// issue x loads for k+1 right after the barrier, compute k, then
// split+write k+1).  X tile uses a chunk-XOR swizzle keyed on (n>>2)&3
// (writes ~4-way spread, reads stay LDS-port-rate); W staging via
// global_load_lds stays linear.  Single barrier per K-step as before.
//   blockIdx.y==0: rows 0..127 = [f;g] -> fgT[b][n][128] split bf16 (3-term)
//   blockIdx.y>=1: rows 128..639 = h   -> h[b][c][n] plain bf16 (single-term)
// ---------------------------------------------------------------------------
__global__ __launch_bounds__(256)
void proj_mfma_kernel(const float* __restrict__ x,
                      const u16* __restrict__ Whi, const u16* __restrict__ Wlo,
                      u16* __restrict__ fgThi, u16* __restrict__ fgTlo,
                      u16* __restrict__ hw) {
  const int b  = blockIdx.z;
  const int n0 = blockIdx.x * 128;
  const int r0 = blockIdx.y * 128;
  const bool fg = (r0 == 0);

  __shared__ u16 Wh[2][128 * 32], Wl[2][128 * 32], Xh[2][128 * 32], Xl[2][128 * 32];

  const int tid = threadIdx.x, wave = tid >> 6, lane = tid & 63;
  const int quad = lane >> 4, l16 = lane & 15;
  const int wa = (wave >> 1) * 64, wb = (wave & 1) * 64;

  // x-staging thread mapping: 4 passes x (8 c-rows x 32 n-chunks)
  const int cN = tid & 31;          // n-chunk (16 B granule along n)
  const int cC = tid >> 5;          // c row within the 8-group

  f32x4 xr[4];
  // load X source for k-slice k0 (4 coalesced f32x4 per thread)
  auto loadX = [&](int k0) {
#pragma unroll
    for (int p = 0; p < 4; ++p) {
      int c = p * 8 + cC;
      xr[p] = *(const f32x4*)&x[((size_t)b * NC + k0 + c) * NN + n0 + cN * 4];
    }
  };
  // split + transposed swizzled write into Xh (and Xl if dolo)
  auto writeX = [&](u16* XhD, u16* XlD, bool dolo) {
#pragma unroll
    for (int p = 0; p < 4; ++p) {
      int c = p * 8 + cC;
      int cc = c >> 3, ce = c & 7;
#pragma unroll
      for (int i = 0; i < 4; ++i) {
        int n = cN * 4 + i;
        int addr = n * 32 + ((cc ^ ((n >> 2) & 3)) << 3) + ce;
        if (dolo) {
          unsigned short hi, lo;
          split2(xr[p][i], hi, lo);
          XhD[addr] = hi;
          XlD[addr] = lo;
        } else {
          XhD[addr] = f32_to_bf16(xr[p][i]);
        }
      }
    }
  };

  f32x4 acc[4][4];
#pragma unroll
  for (int i = 0; i < 4; ++i)
#pragma unroll
    for (int j = 0; j < 4; ++j) acc[i][j] = (f32x4){0.f, 0.f, 0.f, 0.f};

  // prologue: stage k=0 into buf 0
  stage128x32(Whi, r0, NC, 0, Wh[0], tid);
  if (fg) stage128x32(Wlo, r0, NC, 0, Wl[0], tid);
  loadX(0);
  writeX(Xh[0], Xl[0], fg);

  const int KIT = NC / 32;   // 16
  for (int ki = 0; ki < KIT; ++ki) {
    __syncthreads();   // drains vmcnt (W k) + lgkm (X writes k; prior reads)
    const int cur = ki & 1;
    const int nb  = cur ^ 1;
    if (ki + 1 < KIT) {
      const int k1 = (ki + 1) * 32;
      stage128x32(Whi, r0, NC, k1, Wh[nb], tid);
      if (fg) stage128x32(Wlo, r0, NC, k1, Wl[nb], tid);
      loadX(k1);   // in flight across the MFMA burst below
    }

    if (fg) {
      // A=W (r rows, linear), B=X (n rows, swizzled); 3-term split product
      short8 ah[4], al[4], bh[4], bl[4];
#pragma unroll
      for (int i = 0; i < 4; ++i) {
        ah[i] = *(short8*)&Wh[cur][(wa + i * 16 + l16) * 32 + quad * 8];
        al[i] = *(short8*)&Wl[cur][(wa + i * 16 + l16) * 32 + quad * 8];
      }
#pragma unroll
      for (int j = 0; j < 4; ++j) {
        int rr = wb + j * 16 + l16;
        int ci = ((quad ^ ((rr >> 2) & 3)) << 3);
        bh[j] = *(short8*)&Xh[cur][rr * 32 + ci];
        bl[j] = *(short8*)&Xl[cur][rr * 32 + ci];
      }
#pragma unroll
      for (int i = 0; i < 4; ++i)
#pragma unroll
        for (int j = 0; j < 4; ++j) {
          acc[i][j] = __builtin_amdgcn_mfma_f32_16x16x32_bf16(ah[i], bh[j], acc[i][j], 0, 0, 0);
          acc[i][j] = __builtin_amdgcn_mfma_f32_16x16x32_bf16(ah[i], bl[j], acc[i][j], 0, 0, 0);
          acc[i][j] = __builtin_amdgcn_mfma_f32_16x16x32_bf16(al[i], bh[j], acc[i][j], 0, 0, 0);
        }
    } else {
      // A=X (n rows, swizzled), B=W (c rows, linear); single-term hi*hi
      short8 ah[4], bh[4];
#pragma unroll
      for (int i = 0; i < 4; ++i) {
        int rr = wa + i * 16 + l16;
        int ci = ((quad ^ ((rr >> 2) & 3)) << 3);
        ah[i] = *(short8*)&Xh[cur][rr * 32 + ci];
      }
#pragma unroll
      for (int j = 0; j < 4; ++j)
        bh[j] = *(short8*)&Wh[cur][(wb + j * 16 + l16) * 32 + quad * 8];
#pragma unroll
      for (int i = 0; i < 4; ++i)
#pragma unroll
        for (int j = 0; j < 4; ++j)
          acc[i][j] = __builtin_amdgcn_mfma_f32_16x16x32_bf16(ah[i], bh[j], acc[i][j], 0, 0, 0);
    }

    if (ki + 1 < KIT) writeX(Xh[nb], Xl[nb], fg);   // write-late into freed buf
  }

  if (fg) {
#pragma unroll
    for (int i = 0; i < 4; ++i)
#pragma unroll
      for (int j = 0; j < 4; ++j) {
        int rb = wa + i * 16 + quad * 4;
        int n  = n0 + wb + j * 16 + l16;
        ushort4 hi, lo;
        split2(acc[i][j][0], hi.x, lo.x); split2(acc[i][j][1], hi.y, lo.y);
        split2(acc[i][j][2], hi.z, lo.z); split2(acc[i][j][3], hi.w, lo.w);
        size_t off = ((size_t)b * NN + n) * 128 + rb;
        *(ushort4*)&fgThi[off] = hi;
        *(ushort4*)&fgTlo[off] = lo;
      }
  } else {
#pragma unroll
    for (int i = 0; i < 4; ++i)
#pragma unroll
      for (int j = 0; j < 4; ++j) {
        int nb2 = n0 + wa + i * 16 + quad * 4;
        int c  = r0 - 128 + wb + j * 16 + l16;
        ushort4 hi;
        hi.x = f32_to_bf16(acc[i][j][0]); hi.y = f32_to_bf16(acc[i][j][1]);
        hi.z = f32_to_bf16(acc[i][j][2]); hi.w = f32_to_bf16(acc[i][j][3]);
        *(ushort4*)&hw[((size_t)b * NC + c) * NN + nb2] = hi;
      }
  }
}

// ---------------------------------------------------------------------------
// Fused scores+softmax+PV+epilogue (flash-style; E never materialized).
// R9 = revert to the R6 structure (verified 81 us; R4/R5/R8 structural
// probes all regressed -> the serial S->exp->PV chain pins this kernel at
// ~80 us).  m-tile 64, c-tile 256 -> 512 blocks, 2 blocks/CU.  LDS 72 KB:
// F dbuf 32K + H SINGLE 32K + P 8K.  H single-buffer via counted vmcnt:
// H[t] issued at iter top; mid-iter barrier waits vmcnt(2) = H[t] landed
// while F[t+1] stays in flight.  Tail iter -> vmcnt(0).
// ---------------------------------------------------------------------------
__global__ __launch_bounds__(512, 4)
void attn_out_kernel(const u16* __restrict__ fgThi, const u16* __restrict__ fgTlo,
                     const u16* __restrict__ hw, const float* __restrict__ x,
                     const float* __restrict__ gamma, float* __restrict__ out) {
  // XCD pinning: the 32 mt-blocks sharing one (b,ch) hw-panel land on one XCD.
  const int s = blockIdx.x;            // 0..511
  const int xcd = s & 7;
  const int t = s >> 3;                // 0..63
  const int mt = t & 31;               // m-tile 0..31
  const int hi6 = t >> 5;              // 0..1
  const int combo = (hi6 << 3) | xcd;  // 0..15 = (b,ch), bijective
  const int b = combo >> 1;
  const int ch = combo & 1;
  const int m0 = mt * 64;
  const int c0 = ch * 256;

  __shared__ u16 Fh[2][64 * 64], Fl[2][64 * 64];   // f [n][ch] 8 KB each
  __shared__ u16 Hs[256 * 64];                     // h [c][n] 32 KB single
  __shared__ u16 Ps[64 * 64];                      // P [m][n] 8 KB (Dn overlay)
  float* Dn = (float*)Ps;                          // valid after final PV

  const int tid = threadIdx.x, wave = tid >> 6, lane = tid & 63;
  const int quad = lane >> 4, l16 = lane & 15;
  const int ws_n = (wave >> 2) * 32, ws_m = (wave & 3) * 16;   // S partition
  const int wv_c = (wave >> 1) * 64, wv_m = (wave & 1) * 32;   // PV partition

  const size_t frow = (size_t)b * NN;
  const size_t hrow = (size_t)b * NC + c0;

  // g fragments -> registers (iter-invariant; cols 64..127 of fgT)
  short8 gh[2], gl[2];
#pragma unroll
  for (int k = 0; k < 2; ++k) {
    size_t o = (frow + m0 + ws_m + l16) * 128 + 64 + k * 32 + quad * 8;
    gh[k] = *(const short8*)&fgThi[o];
    gl[k] = *(const short8*)&fgTlo[o];
  }

  // prologue: stage F[0] (2 loads/thread) and H[0] (4 loads/thread)
  {
    int flat = tid * 16;
    int row = flat >> 7, chunk = (flat >> 4) & 7;
    int kb = ((chunk ^ (row & 7)) << 4);
    gl_lds16((const char*)(fgThi + (frow + row) * 128) + kb, Fh[0] + (tid & ~63) * 8);
    gl_lds16((const char*)(fgTlo + (frow + row) * 128) + kb, Fl[0] + (tid & ~63) * 8);
#pragma unroll
    for (int s2 = 0; s2 < 4; ++s2) {
      int f2 = s2 * 8192 + tid * 16;
      int r2 = f2 >> 7, c2 = (f2 >> 4) & 7;
      gl_lds16((const char*)(hw + (hrow + r2) * NN) + ((c2 ^ (r2 & 7)) << 4),
               Hs + s2 * 4096 + (tid & ~63) * 8);
    }
  }
  __syncthreads();   // F[0], H[0] landed

  float dsum = 0.f;
  f32x4 ao[4][2];
#pragma unroll
  for (int i = 0; i < 4; ++i)
#pragma unroll
    for (int j = 0; j < 2; ++j) ao[i][j] = (f32x4){0.f, 0.f, 0.f, 0.f};

  const int NT = NN / 64;   // 32
  for (int it = 0; it < NT; ++it) {
    const int cur = it & 1;

    // issue H[it] (skip it=0: prologue did it).  H buffer was freed by the
    // previous iter's trailing __syncthreads.
    if (it > 0) {
      const int n1 = it * 64;
#pragma unroll
      for (int s2 = 0; s2 < 4; ++s2) {
        int f2 = s2 * 8192 + tid * 16;
        int r2 = f2 >> 7, c2 = (f2 >> 4) & 7;
        gl_lds16((const char*)(hw + (hrow + r2) * NN + n1) + ((c2 ^ (r2 & 7)) << 4),
                 Hs + s2 * 4096 + (tid & ~63) * 8);
      }
    }
    // issue F[it+1]
    if (it + 1 < NT) {
      const int n1 = (it + 1) * 64;
      int flat = tid * 16;
      int row = flat >> 7, chunk = (flat >> 4) & 7;
      int kb = ((chunk ^ (row & 7)) << 4);
      gl_lds16((const char*)(fgThi + (frow + n1 + row) * 128) + kb,
               Fh[cur ^ 1] + (tid & ~63) * 8);
      gl_lds16((const char*)(fgTlo + (frow + n1 + row) * 128) + kb,
               Fl[cur ^ 1] + (tid & ~63) * 8);
    }

    // ---- S[it]: S[n64 x m64], 3-term split, g from registers ----
    f32x4 as[2];
#pragma unroll
    for (int i = 0; i < 2; ++i) as[i] = (f32x4){0.f, 0.f, 0.f, 0.f};
#pragma unroll
    for (int k = 0; k < 2; ++k) {
      short8 fh[2], fl[2];
#pragma unroll
      for (int i = 0; i < 2; ++i) {
        int rr = ws_n + i * 16 + l16;
        int ci = (((k * 4 + quad) ^ (rr & 7)) << 3);
        fh[i] = *(short8*)&Fh[cur][rr * 64 + ci];
        fl[i] = *(short8*)&Fl[cur][rr * 64 + ci];
      }
#pragma unroll
      for (int i = 0; i < 2; ++i) {
        as[i] = __builtin_amdgcn_mfma_f32_16x16x32_bf16(fh[i], gh[k], as[i], 0, 0, 0);
        as[i] = __builtin_amdgcn_mfma_f32_16x16x32_bf16(fh[i], gl[k], as[i], 0, 0, 0);
        as[i] = __builtin_amdgcn_mfma_f32_16x16x32_bf16(fl[i], gh[k], as[i], 0, 0, 0);
      }
    }

    // exp + P write (bf16, swizzled [m][n]) + denom partials
    {
      int m = ws_m + l16;
#pragma unroll
      for (int i = 0; i < 2; ++i) {
        float e0 = __expf(as[i][0]);
        float e1 = __expf(as[i][1]);
        float e2 = __expf(as[i][2]);
        float e3 = __expf(as[i][3]);
        dsum += (e0 + e1) + (e2 + e3);
        ushort4 pk;
        pk.x = f32_to_bf16(e0); pk.y = f32_to_bf16(e1);
        pk.z = f32_to_bf16(e2); pk.w = f32_to_bf16(e3);
        int nb = ws_n * 2 + i * 32 + quad * 8;      // byte offset in row
        int chunk = nb >> 4;
        int off = (nb & 15) >> 1;                   // u16 offset in chunk
        *(ushort4*)&Ps[m * 64 + ((chunk ^ (m & 7)) << 3) + off] = pk;
      }
    }

    // mid barrier: H[it] landed (counted vmcnt keeps F[it+1] in flight);
    // P visible via lgkm drain + barrier.
    if (it + 1 < NT) asm volatile("s_waitcnt vmcnt(2)" ::: "memory");
    else             asm volatile("s_waitcnt vmcnt(0)" ::: "memory");
    asm volatile("s_waitcnt lgkmcnt(0)" ::: "memory");
    __builtin_amdgcn_s_barrier();

    // ---- PV[it]: ao[c256 x m64] += h x P ----
#pragma unroll
    for (int k = 0; k < 2; ++k) {
      short8 hh[4], pb[2];
#pragma unroll
      for (int i = 0; i < 4; ++i) {
        int rr = wv_c + i * 16 + l16;
        hh[i] = *(short8*)&Hs[rr * 64 + ((((k * 4 + quad)) ^ (rr & 7)) << 3)];
      }
#pragma unroll
      for (int j = 0; j < 2; ++j) {
        int rm = wv_m + j * 16 + l16;
        pb[j] = *(short8*)&Ps[rm * 64 + ((((k * 4 + quad)) ^ (rm & 7)) << 3)];
      }
#pragma unroll
      for (int i = 0; i < 4; ++i)
#pragma unroll
        for (int j = 0; j < 2; ++j)
          ao[i][j] = __builtin_amdgcn_mfma_f32_16x16x32_bf16(hh[i], pb[j], ao[i][j], 0, 0, 0);
    }

    // iter-end: PV reads done -> H/P buffers free; drains F[it+1] (issued a
    // full phase ago) so next S can read it.
    __syncthreads();
  }

  // ---- epilogue: denom reduce (deterministic, in-block; Dn overlays Ps) ----
  dsum += __shfl_xor(dsum, 16);
  dsum += __shfl_xor(dsum, 32);
  if (tid < 64) Dn[tid] = 0.f;
  __syncthreads();
  if (quad == 0) atomicAdd(&Dn[ws_m + l16], dsum);
  __syncthreads();

  const float g = gamma[0];
  float invd[2];
#pragma unroll
  for (int j = 0; j < 2; ++j)
    invd[j] = g / Dn[wv_m + j * 16 + l16];

#pragma unroll
  for (int i = 0; i < 4; ++i) {
#pragma unroll
    for (int j = 0; j < 2; ++j) {
      const int c = c0 + wv_c + i * 16 + quad * 4;
      const int m = m0 + wv_m + j * 16 + l16;
#pragma unroll
      for (int r = 0; r < 4; ++r) {
        size_t off = ((size_t)b * NC + c + r) * NN + m;
        out[off] = fmaf(invd[j], ao[i][j][r], x[off]);
      }
    }
  }
}

// ---------------------------------------------------------------------------
extern "C" void kernel_launch(void* const* d_in, const int* in_sizes, int n_in,
                              void* d_out, int out_size, void* d_ws, size_t ws_size,
                              hipStream_t stream) {
  const float* x     = (const float*)d_in[0];
  const float* Wq    = (const float*)d_in[1];
  const float* Wk    = (const float*)d_in[2];
  const float* Wv    = (const float*)d_in[3];
  const float* gamma = (const float*)d_in[4];
  float* out = (float*)d_out;

  // Workspace (xThi/xTlo eliminated by the proj fusion):
  //   [33,554,432 ) Whi  bf16 [640][512]           655,360
  //   [34,209,792 ) Wlo                            655,360
  //   [67,108,864 ) fgThi bf16 [8][2048][128]    4,194,304
  //   [71,303,168 ) fgTlo                        4,194,304
  //   [75,497,472 ) hw    bf16 [8][512][2048]   16,777,216
  char* ws = (char*)d_ws;
  u16*   Whi   = (u16*)(ws + 33554432);
  u16*   Wlo   = (u16*)(ws + 34209792);
  u16*   fgThi = (u16*)(ws + 67108864);
  u16*   fgTlo = (u16*)(ws + 71303168);
  u16*   hw    = (u16*)(ws + 75497472);

  wsplit_kernel<<<dim3(320), 256, 0, stream>>>(Wq, Wk, Wv, Whi, Wlo);
  proj_mfma_kernel<<<dim3(NN / 128, 5, NB), 256, 0, stream>>>(
      x, Whi, Wlo, fgThi, fgTlo, hw);
  attn_out_kernel<<<dim3(512), 512, 0, stream>>>(fgThi, fgTlo, hw, x, gamma, out);
}

// Round 11
// 199.241 us; speedup vs baseline: 1.3298x; 1.0742x over previous
//
#include <hip/hip_runtime.h>
#include <hip/hip_bf16.h>
#include <math.h>

// Problem dims (fixed by the reference)
#define NB 8
#define NC 512
#define NN 2048

typedef unsigned short u16;
typedef __attribute__((ext_vector_type(8))) short short8;
typedef __attribute__((ext_vector_type(4))) float f32x4;

__device__ __forceinline__ float bf16_to_f32(u16 v) {
  union { unsigned int u; float f; } c; c.u = ((unsigned int)v) << 16; return c.f;
}
__device__ __forceinline__ u16 f32_to_bf16(float f) {
  __hip_bfloat16 h = __float2bfloat16(f);   // RNE
  union { __hip_bfloat16 h; u16 u; } c; c.h = h; return c.u;
}
__device__ __forceinline__ void split2(float v, unsigned short& hi, unsigned short& lo) {
  hi = f32_to_bf16(v);
  lo = f32_to_bf16(v - bf16_to_f32(hi));
}

__device__ __forceinline__ void gl_lds16(const void* g, void* l) {
  __builtin_amdgcn_global_load_lds(
      (const __attribute__((address_space(1))) unsigned int*)g,
      (__attribute__((address_space(3))) unsigned int*)l, 16, 0, 0);
}

// stage 128 rows x 32 u16 (64 B/row, 8 KB) into LDS via global_load_lds w=16.
__device__ __forceinline__ void stage128x32(const u16* __restrict__ src, size_t row_base,
                                            int selems, int k0, u16* lds, int tid) {
#pragma unroll
  for (int s = 0; s < 2; ++s) {
    int flat = s * 4096 + tid * 16;   // byte offset within tile
    int row = flat >> 6;
    int kb  = flat & 63;
    const char* g = (const char*)(src + (row_base + row) * (size_t)selems + k0) + kb;
    u16* l = lds + s * 2048 + (tid & ~63) * 8;  // wave-uniform base; HW adds lane*16
    gl_lds16(g, l);
  }
}

// ---------------------------------------------------------------------------
// x transpose + split: x[b][c][n] fp32 -> xThi/xTlo[b][n][c] bf16.
// R11: wsplit FOLDED IN — the first 320 flat blocks also convert one
// 1024-elem chunk of [Wq;Wk;Wv] -> Whi/Wlo (W work is 1.3 MB vs xsplit's
// 100 MB: cost ~0, saves one kernel launch + gap).
// ---------------------------------------------------------------------------
__global__ __launch_bounds__(256)
void xsplit_kernel(const float* __restrict__ x,
                   const float* __restrict__ Wq, const float* __restrict__ Wk,
                   const float* __restrict__ Wv,
                   u16* __restrict__ xThi, u16* __restrict__ xTlo,
                   u16* __restrict__ Whi, u16* __restrict__ Wlo) {
  const int b = blockIdx.z, c0 = blockIdx.y * 64, n0 = blockIdx.x * 64;
  const int tid = threadIdx.x;

  // --- merged W split (first 320 flat blocks; no LDS, before any barrier) ---
  int fid = blockIdx.x + 32 * (blockIdx.y + 8 * blockIdx.z);
  if (fid < 320) {
    int idx = (fid * 256 + tid) * 4;   // 640*512 total, exact
    int r = idx >> 9, c = idx & 511;
    const float* src;
    if (r < 64)       src = Wq + (size_t)r * NC + c;
    else if (r < 128) src = Wk + (size_t)(r - 64) * NC + c;
    else              src = Wv + (size_t)(r - 128) * NC + c;
    float4 v = *(const float4*)src;
    ushort4 hi, lo;
    split2(v.x, hi.x, lo.x); split2(v.y, hi.y, lo.y);
    split2(v.z, hi.z, lo.z); split2(v.w, hi.w, lo.w);
    *(ushort4*)&Whi[idx] = hi;
    *(ushort4*)&Wlo[idx] = lo;
  }

  __shared__ float t[64][65];
  const int tx = tid & 15, ty = tid >> 4;
#pragma unroll
  for (int r = 0; r < 4; ++r) {
    int c = r * 16 + ty;
    float4 v = *(const float4*)&x[((size_t)b * NC + c0 + c) * NN + n0 + tx * 4];
    t[c][tx * 4 + 0] = v.x; t[c][tx * 4 + 1] = v.y;
    t[c][tx * 4 + 2] = v.z; t[c][tx * 4 + 3] = v.w;
  }
  __syncthreads();
#pragma unroll
  for (int r = 0; r < 4; ++r) {
    int n = r * 16 + ty;
    ushort4 hi, lo;
    split2(t[tx * 4 + 0][n], hi.x, lo.x);
    split2(t[tx * 4 + 1][n], hi.y, lo.y);
    split2(t[tx * 4 + 2][n], hi.z, lo.z);
    split2(t[tx * 4 + 3][n], hi.w, lo.w);
    size_t off = ((size_t)b * NN + n0 + n) * NC + c0 + tx * 4;
    *(ushort4*)&xThi[off] = hi;
    *(ushort4*)&xTlo[off] = lo;
  }
}

// ---------------------------------------------------------------------------
// Projections, MFMA.  Double-buffered LDS + SINGLE barrier per K-step
// (exact R6 source — verified in the 200.9 us run).
//   blockIdx.y==0: rows 0..127 = [f;g] -> fgT[b][n][128] split bf16 (3-term)
//   blockIdx.y>=1: rows 128..639 = h   -> h[b][c][n] plain bf16 (single-term)
// ---------------------------------------------------------------------------
__global__ __launch_bounds__(256)
void proj_mfma_kernel(const u16* __restrict__ xThi, const u16* __restrict__ xTlo,
                      const u16* __restrict__ Whi, const u16* __restrict__ Wlo,
                      u16* __restrict__ fgThi, u16* __restrict__ fgTlo,
                      u16* __restrict__ hw) {
  const int b  = blockIdx.z;
  const int n0 = blockIdx.x * 128;
  const int r0 = blockIdx.y * 128;
  const bool fg = (r0 == 0);

  __shared__ u16 Wh[2][128 * 32], Wl[2][128 * 32], Xh[2][128 * 32], Xl[2][128 * 32];

  const int tid = threadIdx.x, wave = tid >> 6, lane = tid & 63;
  const int quad = lane >> 4, l16 = lane & 15;
  const int wa = (wave >> 1) * 64, wb = (wave & 1) * 64;
  const size_t xrow = (size_t)b * NN + n0;

  f32x4 acc[4][4];
#pragma unroll
  for (int i = 0; i < 4; ++i)
#pragma unroll
    for (int j = 0; j < 4; ++j) acc[i][j] = (f32x4){0.f, 0.f, 0.f, 0.f};

  // prologue: stage k=0 into buf 0
  stage128x32(Whi, r0, NC, 0, Wh[0], tid);
  stage128x32(xThi, xrow, NC, 0, Xh[0], tid);
  if (fg) {
    stage128x32(Wlo, r0, NC, 0, Wl[0], tid);
    stage128x32(xTlo, xrow, NC, 0, Xl[0], tid);
  }

  const int KIT = NC / 32;   // 16
  for (int ki = 0; ki < KIT; ++ki) {
    __syncthreads();   // drains vmcnt -> buf[ki&1] ready; lgkm -> prior reads done
    if (ki + 1 < KIT) {
      const int nb = (ki + 1) & 1, k1 = (ki + 1) * 32;
      stage128x32(Whi, r0, NC, k1, Wh[nb], tid);
      stage128x32(xThi, xrow, NC, k1, Xh[nb], tid);
      if (fg) {
        stage128x32(Wlo, r0, NC, k1, Wl[nb], tid);
        stage128x32(xTlo, xrow, NC, k1, Xl[nb], tid);
      }
    }
    const int cur = ki & 1;

    if (fg) {
      short8 ah[4], al[4], bh[4], bl[4];
#pragma unroll
      for (int i = 0; i < 4; ++i) {
        ah[i] = *(short8*)&Wh[cur][(wa + i * 16 + l16) * 32 + quad * 8];
        al[i] = *(short8*)&Wl[cur][(wa + i * 16 + l16) * 32 + quad * 8];
      }
#pragma unroll
      for (int j = 0; j < 4; ++j) {
        bh[j] = *(short8*)&Xh[cur][(wb + j * 16 + l16) * 32 + quad * 8];
        bl[j] = *(short8*)&Xl[cur][(wb + j * 16 + l16) * 32 + quad * 8];
      }
#pragma unroll
      for (int i = 0; i < 4; ++i)
#pragma unroll
        for (int j = 0; j < 4; ++j) {
          acc[i][j] = __builtin_amdgcn_mfma_f32_16x16x32_bf16(ah[i], bh[j], acc[i][j], 0, 0, 0);
          acc[i][j] = __builtin_amdgcn_mfma_f32_16x16x32_bf16(ah[i], bl[j], acc[i][j], 0, 0, 0);
          acc[i][j] = __builtin_amdgcn_mfma_f32_16x16x32_bf16(al[i], bh[j], acc[i][j], 0, 0, 0);
        }
    } else {
      short8 ah[4], bh[4];
#pragma unroll
      for (int i = 0; i < 4; ++i)
        ah[i] = *(short8*)&Xh[cur][(wa + i * 16 + l16) * 32 + quad * 8];
#pragma unroll
      for (int j = 0; j < 4; ++j)
        bh[j] = *(short8*)&Wh[cur][(wb + j * 16 + l16) * 32 + quad * 8];
#pragma unroll
      for (int i = 0; i < 4; ++i)
#pragma unroll
        for (int j = 0; j < 4; ++j)
          acc[i][j] = __builtin_amdgcn_mfma_f32_16x16x32_bf16(ah[i], bh[j], acc[i][j], 0, 0, 0);
    }
  }

  if (fg) {
#pragma unroll
    for (int i = 0; i < 4; ++i)
#pragma unroll
      for (int j = 0; j < 4; ++j) {
        int rb = wa + i * 16 + quad * 4;
        int n  = n0 + wb + j * 16 + l16;
        ushort4 hi, lo;
        split2(acc[i][j][0], hi.x, lo.x); split2(acc[i][j][1], hi.y, lo.y);
        split2(acc[i][j][2], hi.z, lo.z); split2(acc[i][j][3], hi.w, lo.w);
        size_t off = ((size_t)b * NN + n) * 128 + rb;
        *(ushort4*)&fgThi[off] = hi;
        *(ushort4*)&fgTlo[off] = lo;
      }
  } else {
#pragma unroll
    for (int i = 0; i < 4; ++i)
#pragma unroll
      for (int j = 0; j < 4; ++j) {
        int nb = n0 + wa + i * 16 + quad * 4;
        int c  = r0 - 128 + wb + j * 16 + l16;
        ushort4 hi;
        hi.x = f32_to_bf16(acc[i][j][0]); hi.y = f32_to_bf16(acc[i][j][1]);
        hi.z = f32_to_bf16(acc[i][j][2]); hi.w = f32_to_bf16(acc[i][j][3]);
        *(ushort4*)&hw[((size_t)b * NC + c) * NN + nb] = hi;
      }
  }
}

// ---------------------------------------------------------------------------
// Fused scores+softmax+PV+epilogue (flash-style; E never materialized).
// Exact R6 source (verified 81.0/79.4 us).  m-tile 64, c-tile 256 ->
// 512 blocks, 2 blocks/CU.  LDS 72 KB: F dbuf 32K + H SINGLE 32K + P 8K.
// H single-buffer via counted vmcnt: H[t] issued at iter top; mid-iter
// barrier waits vmcnt(2) = H[t] landed while F[t+1] stays in flight.
// ---------------------------------------------------------------------------
__global__ __launch_bounds__(512, 4)
void attn_out_kernel(const u16* __restrict__ fgThi, const u16* __restrict__ fgTlo,
                     const u16* __restrict__ hw, const float* __restrict__ x,
                     const float* __restrict__ gamma, float* __restrict__ out) {
  // XCD pinning: the 32 mt-blocks sharing one (b,ch) hw-panel land on one XCD.
  const int s = blockIdx.x;            // 0..511
  const int xcd = s & 7;
  const int t = s >> 3;                // 0..63
  const int mt = t & 31;               // m-tile 0..31
  const int hi6 = t >> 5;              // 0..1
  const int combo = (hi6 << 3) | xcd;  // 0..15 = (b,ch), bijective
  const int b = combo >> 1;
  const int ch = combo & 1;
  const int m0 = mt * 64;
  const int c0 = ch * 256;

  __shared__ u16 Fh[2][64 * 64], Fl[2][64 * 64];   // f [n][ch] 8 KB each
  __shared__ u16 Hs[256 * 64];                     // h [c][n] 32 KB single
  __shared__ u16 Ps[64 * 64];                      // P [m][n] 8 KB (Dn overlay)
  float* Dn = (float*)Ps;                          // valid after final PV

  const int tid = threadIdx.x, wave = tid >> 6, lane = tid & 63;
  const int quad = lane >> 4, l16 = lane & 15;
  const int ws_n = (wave >> 2) * 32, ws_m = (wave & 3) * 16;   // S partition
  const int wv_c = (wave >> 1) * 64, wv_m = (wave & 1) * 32;   // PV partition

  const size_t frow = (size_t)b * NN;
  const size_t hrow = (size_t)b * NC + c0;

  // g fragments -> registers (iter-invariant; cols 64..127 of fgT)
  short8 gh[2], gl[2];
#pragma unroll
  for (int k = 0; k < 2; ++k) {
    size_t o = (frow + m0 + ws_m + l16) * 128 + 64 + k * 32 + quad * 8;
    gh[k] = *(const short8*)&fgThi[o];
    gl[k] = *(const short8*)&fgTlo[o];
  }

  // prologue: stage F[0] (2 loads/thread) and H[0] (4 loads/thread)
  {
    int flat = tid * 16;
    int row = flat >> 7, chunk = (flat >> 4) & 7;
    int kb = ((chunk ^ (row & 7)) << 4);
    gl_lds16((const char*)(fgThi + (frow + row) * 128) + kb, Fh[0] + (tid & ~63) * 8);
    gl_lds16((const char*)(fgTlo + (frow + row) * 128) + kb, Fl[0] + (tid & ~63) * 8);
#pragma unroll
    for (int s2 = 0; s2 < 4; ++s2) {
      int f2 = s2 * 8192 + tid * 16;
      int r2 = f2 >> 7, c2 = (f2 >> 4) & 7;
      gl_lds16((const char*)(hw + (hrow + r2) * NN) + ((c2 ^ (r2 & 7)) << 4),
               Hs + s2 * 4096 + (tid & ~63) * 8);
    }
  }
  __syncthreads();   // F[0], H[0] landed

  float dsum = 0.f;
  f32x4 ao[4][2];
#pragma unroll
  for (int i = 0; i < 4; ++i)
#pragma unroll
    for (int j = 0; j < 2; ++j) ao[i][j] = (f32x4){0.f, 0.f, 0.f, 0.f};

  const int NT = NN / 64;   // 32
  for (int it = 0; it < NT; ++it) {
    const int cur = it & 1;

    // issue H[it] (skip it=0: prologue did it).  H buffer was freed by the
    // previous iter's trailing __syncthreads.
    if (it > 0) {
      const int n1 = it * 64;
#pragma unroll
      for (int s2 = 0; s2 < 4; ++s2) {
        int f2 = s2 * 8192 + tid * 16;
        int r2 = f2 >> 7, c2 = (f2 >> 4) & 7;
        gl_lds16((const char*)(hw + (hrow + r2) * NN + n1) + ((c2 ^ (r2 & 7)) << 4),
                 Hs + s2 * 4096 + (tid & ~63) * 8);
      }
    }
    // issue F[it+1]
    if (it + 1 < NT) {
      const int n1 = (it + 1) * 64;
      int flat = tid * 16;
      int row = flat >> 7, chunk = (flat >> 4) & 7;
      int kb = ((chunk ^ (row & 7)) << 4);
      gl_lds16((const char*)(fgThi + (frow + n1 + row) * 128) + kb,
               Fh[cur ^ 1] + (tid & ~63) * 8);
      gl_lds16((const char*)(fgTlo + (frow + n1 + row) * 128) + kb,
               Fl[cur ^ 1] + (tid & ~63) * 8);
    }

    // ---- S[it]: S[n64 x m64], 3-term split, g from registers ----
    f32x4 as[2];
#pragma unroll
    for (int i = 0; i < 2; ++i) as[i] = (f32x4){0.f, 0.f, 0.f, 0.f};
#pragma unroll
    for (int k = 0; k < 2; ++k) {
      short8 fh[2], fl[2];
#pragma unroll
      for (int i = 0; i < 2; ++i) {
        int rr = ws_n + i * 16 + l16;
        int ci = (((k * 4 + quad) ^ (rr & 7)) << 3);
        fh[i] = *(short8*)&Fh[cur][rr * 64 + ci];
        fl[i] = *(short8*)&Fl[cur][rr * 64 + ci];
      }
#pragma unroll
      for (int i = 0; i < 2; ++i) {
        as[i] = __builtin_amdgcn_mfma_f32_16x16x32_bf16(fh[i], gh[k], as[i], 0, 0, 0);
        as[i] = __builtin_amdgcn_mfma_f32_16x16x32_bf16(fh[i], gl[k], as[i], 0, 0, 0);
        as[i] = __builtin_amdgcn_mfma_f32_16x16x32_bf16(fl[i], gh[k], as[i], 0, 0, 0);
      }
    }

    // exp + P write (bf16, swizzled [m][n]) + denom partials
    {
      int m = ws_m + l16;
#pragma unroll
      for (int i = 0; i < 2; ++i) {
        float e0 = __expf(as[i][0]);
        float e1 = __expf(as[i][1]);
        float e2 = __expf(as[i][2]);
        float e3 = __expf(as[i][3]);
        dsum += (e0 + e1) + (e2 + e3);
        ushort4 pk;
        pk.x = f32_to_bf16(e0); pk.y = f32_to_bf16(e1);
        pk.z = f32_to_bf16(e2); pk.w = f32_to_bf16(e3);
        int nb = ws_n * 2 + i * 32 + quad * 8;      // byte offset in row
        int chunk = nb >> 4;
        int off = (nb & 15) >> 1;                   // u16 offset in chunk
        *(ushort4*)&Ps[m * 64 + ((chunk ^ (m & 7)) << 3) + off] = pk;
      }
    }

    // mid barrier: H[it] landed (counted vmcnt keeps F[it+1] in flight);
    // P visible via lgkm drain + barrier.
    if (it + 1 < NT) asm volatile("s_waitcnt vmcnt(2)" ::: "memory");
    else             asm volatile("s_waitcnt vmcnt(0)" ::: "memory");
    asm volatile("s_waitcnt lgkmcnt(0)" ::: "memory");
    __builtin_amdgcn_s_barrier();

    // ---- PV[it]: ao[c256 x m64] += h x P ----
#pragma unroll
    for (int k = 0; k < 2; ++k) {
      short8 hh[4], pb[2];
#pragma unroll
      for (int i = 0; i < 4; ++i) {
        int rr = wv_c + i * 16 + l16;
        hh[i] = *(short8*)&Hs[rr * 64 + ((((k * 4 + quad)) ^ (rr & 7)) << 3)];
      }
#pragma unroll
      for (int j = 0; j < 2; ++j) {
        int rm = wv_m + j * 16 + l16;
        pb[j] = *(short8*)&Ps[rm * 64 + ((((k * 4 + quad)) ^ (rm & 7)) << 3)];
      }
#pragma unroll
      for (int i = 0; i < 4; ++i)
#pragma unroll
        for (int j = 0; j < 2; ++j)
          ao[i][j] = __builtin_amdgcn_mfma_f32_16x16x32_bf16(hh[i], pb[j], ao[i][j], 0, 0, 0);
    }

    // iter-end: PV reads done -> H/P buffers free; drains F[it+1] (issued a
    // full phase ago) so next S can read it.
    __syncthreads();
  }

  // ---- epilogue: denom reduce (deterministic, in-block; Dn overlays Ps) ----
  dsum += __shfl_xor(dsum, 16);
  dsum += __shfl_xor(dsum, 32);
  if (tid < 64) Dn[tid] = 0.f;
  __syncthreads();
  if (quad == 0) atomicAdd(&Dn[ws_m + l16], dsum);
  __syncthreads();

  const float g = gamma[0];
  float invd[2];
#pragma unroll
  for (int j = 0; j < 2; ++j)
    invd[j] = g / Dn[wv_m + j * 16 + l16];

#pragma unroll
  for (int i = 0; i < 4; ++i) {
#pragma unroll
    for (int j = 0; j < 2; ++j) {
      const int c = c0 + wv_c + i * 16 + quad * 4;
      const int m = m0 + wv_m + j * 16 + l16;
#pragma unroll
      for (int r = 0; r < 4; ++r) {
        size_t off = ((size_t)b * NC + c + r) * NN + m;
        out[off] = fmaf(invd[j], ao[i][j][r], x[off]);
      }
    }
  }
}

// ---------------------------------------------------------------------------
extern "C" void kernel_launch(void* const* d_in, const int* in_sizes, int n_in,
                              void* d_out, int out_size, void* d_ws, size_t ws_size,
                              hipStream_t stream) {
  const float* x     = (const float*)d_in[0];
  const float* Wq    = (const float*)d_in[1];
  const float* Wk    = (const float*)d_in[2];
  const float* Wv    = (const float*)d_in[3];
  const float* gamma = (const float*)d_in[4];
  float* out = (float*)d_out;

  // Workspace (R6 layout):
  //   [0          ) xThi bf16 [8][2048][512]   16,777,216
  //   [16,777,216 ) xTlo                        16,777,216
  //   [33,554,432 ) Whi  bf16 [640][512]           655,360
  //   [34,209,792 ) Wlo                            655,360
  //   [67,108,864 ) fgThi bf16 [8][2048][128]    4,194,304
  //   [71,303,168 ) fgTlo                        4,194,304
  //   [75,497,472 ) hw    bf16 [8][512][2048]   16,777,216
  char* ws = (char*)d_ws;
  u16*   xThi  = (u16*)ws;
  u16*   xTlo  = (u16*)(ws + 16777216);
  u16*   Whi   = (u16*)(ws + 33554432);
  u16*   Wlo   = (u16*)(ws + 34209792);
  u16*   fgThi = (u16*)(ws + 67108864);
  u16*   fgTlo = (u16*)(ws + 71303168);
  u16*   hw    = (u16*)(ws + 75497472);

  xsplit_kernel<<<dim3(NN / 64, NC / 64, NB), 256, 0, stream>>>(
      x, Wq, Wk, Wv, xThi, xTlo, Whi, Wlo);
  proj_mfma_kernel<<<dim3(NN / 128, 5, NB), 256, 0, stream>>>(
      xThi, xTlo, Whi, Wlo, fgThi, fgTlo, hw);
  attn_out_kernel<<<dim3(512), 512, 0, stream>>>(fgThi, fgTlo, hw, x, gamma, out);
}

// Round 14
// 191.223 us; speedup vs baseline: 1.3856x; 1.0419x over previous
//
#include <hip/hip_runtime.h>
#include <hip/hip_bf16.h>
#include <math.h>

// Problem dims (fixed by the reference)
#define NB 8
#define NC 512
#define NN 2048

typedef unsigned short u16;
typedef __attribute__((ext_vector_type(8))) short short8;
typedef __attribute__((ext_vector_type(4))) float f32x4;

__device__ __forceinline__ float bf16_to_f32(u16 v) {
  union { unsigned int u; float f; } c; c.u = ((unsigned int)v) << 16; return c.f;
}
__device__ __forceinline__ u16 f32_to_bf16(float f) {
  __hip_bfloat16 h = __float2bfloat16(f);   // RNE
  union { __hip_bfloat16 h; u16 u; } c; c.h = h; return c.u;
}
__device__ __forceinline__ void split2(float v, unsigned short& hi, unsigned short& lo) {
  hi = f32_to_bf16(v);
  lo = f32_to_bf16(v - bf16_to_f32(hi));
}

__device__ __forceinline__ void gl_lds16(const void* g, void* l) {
  __builtin_amdgcn_global_load_lds(
      (const __attribute__((address_space(1))) unsigned int*)g,
      (__attribute__((address_space(3))) unsigned int*)l, 16, 0, 0);
}

// stage 128 rows x 32 u16 (64 B/row, 8 KB) into LDS via global_load_lds w=16.
__device__ __forceinline__ void stage128x32(const u16* __restrict__ src, size_t row_base,
                                            int selems, int k0, u16* lds, int tid) {
#pragma unroll
  for (int s = 0; s < 2; ++s) {
    int flat = s * 4096 + tid * 16;   // byte offset within tile
    int row = flat >> 6;
    int kb  = flat & 63;
    const char* g = (const char*)(src + (row_base + row) * (size_t)selems + k0) + kb;
    u16* l = lds + s * 2048 + (tid & ~63) * 8;  // wave-uniform base; HW adds lane*16
    gl_lds16(g, l);
  }
}

// stage 64 rows x 32 u16 (64 B/row, 4 KB): 1 load/thread at 256 threads.
__device__ __forceinline__ void stage64x32(const u16* __restrict__ src, size_t row_base,
                                           int selems, int k0, u16* lds, int tid) {
  int flat = tid * 16;
  int row = flat >> 6;
  int kb  = flat & 63;
  const char* g = (const char*)(src + (row_base + row) * (size_t)selems + k0) + kb;
  gl_lds16(g, lds + (tid & ~63) * 8);
}

// ---------------------------------------------------------------------------
// x transpose + split: x[b][c][n] fp32 -> xThi/xTlo[b][n][c] bf16.
// wsplit folded in (R11, verified): first 320 flat blocks also convert one
// 1024-elem chunk of [Wq;Wk;Wv] -> Whi/Wlo.
// ---------------------------------------------------------------------------
__global__ __launch_bounds__(256)
void xsplit_kernel(const float* __restrict__ x,
                   const float* __restrict__ Wq, const float* __restrict__ Wk,
                   const float* __restrict__ Wv,
                   u16* __restrict__ xThi, u16* __restrict__ xTlo,
                   u16* __restrict__ Whi, u16* __restrict__ Wlo) {
  const int b = blockIdx.z, c0 = blockIdx.y * 64, n0 = blockIdx.x * 64;
  const int tid = threadIdx.x;

  // --- merged W split (first 320 flat blocks; no LDS, before any barrier) ---
  int fid = blockIdx.x + 32 * (blockIdx.y + 8 * blockIdx.z);
  if (fid < 320) {
    int idx = (fid * 256 + tid) * 4;   // 640*512 total, exact
    int r = idx >> 9, c = idx & 511;
    const float* src;
    if (r < 64)       src = Wq + (size_t)r * NC + c;
    else if (r < 128) src = Wk + (size_t)(r - 64) * NC + c;
    else              src = Wv + (size_t)(r - 128) * NC + c;
    float4 v = *(const float4*)src;
    ushort4 hi, lo;
    split2(v.x, hi.x, lo.x); split2(v.y, hi.y, lo.y);
    split2(v.z, hi.z, lo.z); split2(v.w, hi.w, lo.w);
    *(ushort4*)&Whi[idx] = hi;
    *(ushort4*)&Wlo[idx] = lo;
  }

  __shared__ float t[64][65];
  const int tx = tid & 15, ty = tid >> 4;
#pragma unroll
  for (int r = 0; r < 4; ++r) {
    int c = r * 16 + ty;
    float4 v = *(const float4*)&x[((size_t)b * NC + c0 + c) * NN + n0 + tx * 4];
    t[c][tx * 4 + 0] = v.x; t[c][tx * 4 + 1] = v.y;
    t[c][tx * 4 + 2] = v.z; t[c][tx * 4 + 3] = v.w;
  }
  __syncthreads();
#pragma unroll
  for (int r = 0; r < 4; ++r) {
    int n = r * 16 + ty;
    ushort4 hi, lo;
    split2(t[tx * 4 + 0][n], hi.x, lo.x);
    split2(t[tx * 4 + 1][n], hi.y, lo.y);
    split2(t[tx * 4 + 2][n], hi.z, lo.z);
    split2(t[tx * 4 + 3][n], hi.w, lo.w);
    size_t off = ((size_t)b * NN + n0 + n) * NC + c0 + tx * 4;
    *(ushort4*)&xThi[off] = hi;
    *(ushort4*)&xTlo[off] = lo;
  }
}

// ---------------------------------------------------------------------------
// proj_fg: rows 0..127 = [f;g] -> fgT[b][n][128], 3-term split product.
// R12 re-tile: 64r x 128n per block -> 256 blocks (= 1/CU, full machine
// coverage for this heavy panel; was 128 hetero blocks inside a 640 grid).
// Same verified staging/fragment/swizzle pattern; LDS 48 KB.
// ---------------------------------------------------------------------------
__global__ __launch_bounds__(256)
void proj_fg_kernel(const u16* __restrict__ xThi, const u16* __restrict__ xTlo,
                    const u16* __restrict__ Whi, const u16* __restrict__ Wlo,
                    u16* __restrict__ fgThi, u16* __restrict__ fgTlo) {
  const int b  = blockIdx.z;
  const int n0 = blockIdx.x * 128;
  const int r0 = blockIdx.y * 64;     // 0 (f) or 64 (g)

  __shared__ u16 Wh[2][64 * 32], Wl[2][64 * 32], Xh[2][128 * 32], Xl[2][128 * 32];

  const int tid = threadIdx.x, wave = tid >> 6, lane = tid & 63;
  const int quad = lane >> 4, l16 = lane & 15;
  const int wa = (wave >> 1) * 32, wb = (wave & 1) * 64;
  const size_t xrow = (size_t)b * NN + n0;

  f32x4 acc[2][4];
#pragma unroll
  for (int i = 0; i < 2; ++i)
#pragma unroll
    for (int j = 0; j < 4; ++j) acc[i][j] = (f32x4){0.f, 0.f, 0.f, 0.f};

  // prologue: stage k=0 into buf 0
  stage64x32(Whi, r0, NC, 0, Wh[0], tid);
  stage64x32(Wlo, r0, NC, 0, Wl[0], tid);
  stage128x32(xThi, xrow, NC, 0, Xh[0], tid);
  stage128x32(xTlo, xrow, NC, 0, Xl[0], tid);

  const int KIT = NC / 32;   // 16
  for (int ki = 0; ki < KIT; ++ki) {
    __syncthreads();
    if (ki + 1 < KIT) {
      const int nb = (ki + 1) & 1, k1 = (ki + 1) * 32;
      stage64x32(Whi, r0, NC, k1, Wh[nb], tid);
      stage64x32(Wlo, r0, NC, k1, Wl[nb], tid);
      stage128x32(xThi, xrow, NC, k1, Xh[nb], tid);
      stage128x32(xTlo, xrow, NC, k1, Xl[nb], tid);
    }
    const int cur = ki & 1;

    short8 ah[2], al[2], bh[4], bl[4];
#pragma unroll
    for (int i = 0; i < 2; ++i) {
      ah[i] = *(short8*)&Wh[cur][(wa + i * 16 + l16) * 32 + quad * 8];
      al[i] = *(short8*)&Wl[cur][(wa + i * 16 + l16) * 32 + quad * 8];
    }
#pragma unroll
    for (int j = 0; j < 4; ++j) {
      bh[j] = *(short8*)&Xh[cur][(wb + j * 16 + l16) * 32 + quad * 8];
      bl[j] = *(short8*)&Xl[cur][(wb + j * 16 + l16) * 32 + quad * 8];
    }
#pragma unroll
    for (int i = 0; i < 2; ++i)
#pragma unroll
      for (int j = 0; j < 4; ++j) {
        acc[i][j] = __builtin_amdgcn_mfma_f32_16x16x32_bf16(ah[i], bh[j], acc[i][j], 0, 0, 0);
        acc[i][j] = __builtin_amdgcn_mfma_f32_16x16x32_bf16(ah[i], bl[j], acc[i][j], 0, 0, 0);
        acc[i][j] = __builtin_amdgcn_mfma_f32_16x16x32_bf16(al[i], bh[j], acc[i][j], 0, 0, 0);
      }
  }

#pragma unroll
  for (int i = 0; i < 2; ++i)
#pragma unroll
    for (int j = 0; j < 4; ++j) {
      int rb = r0 + wa + i * 16 + quad * 4;
      int n  = n0 + wb + j * 16 + l16;
      ushort4 hi, lo;
      split2(acc[i][j][0], hi.x, lo.x); split2(acc[i][j][1], hi.y, lo.y);
      split2(acc[i][j][2], hi.z, lo.z); split2(acc[i][j][3], hi.w, lo.w);
      size_t off = ((size_t)b * NN + n) * 128 + rb;
      *(ushort4*)&fgThi[off] = hi;
      *(ushort4*)&fgTlo[off] = lo;
    }
}

// ---------------------------------------------------------------------------
// proj_h: rows 128..639 = h -> hw[b][c][n] bf16 (single-term hi*hi).
// Exact R6/R11 h-path code; grid is now uniform 512 blocks = exactly 2/CU.
// ---------------------------------------------------------------------------
__global__ __launch_bounds__(256)
void proj_h_kernel(const u16* __restrict__ xThi, const u16* __restrict__ Whi,
                   u16* __restrict__ hw) {
  const int b  = blockIdx.z;
  const int n0 = blockIdx.x * 128;
  const int r0 = 128 + blockIdx.y * 128;

  __shared__ u16 Wh[2][128 * 32], Xh[2][128 * 32];

  const int tid = threadIdx.x, wave = tid >> 6, lane = tid & 63;
  const int quad = lane >> 4, l16 = lane & 15;
  const int wa = (wave >> 1) * 64, wb = (wave & 1) * 64;
  const size_t xrow = (size_t)b * NN + n0;

  f32x4 acc[4][4];
#pragma unroll
  for (int i = 0; i < 4; ++i)
#pragma unroll
    for (int j = 0; j < 4; ++j) acc[i][j] = (f32x4){0.f, 0.f, 0.f, 0.f};

  stage128x32(Whi, r0, NC, 0, Wh[0], tid);
  stage128x32(xThi, xrow, NC, 0, Xh[0], tid);

  const int KIT = NC / 32;   // 16
  for (int ki = 0; ki < KIT; ++ki) {
    __syncthreads();
    if (ki + 1 < KIT) {
      const int nb = (ki + 1) & 1, k1 = (ki + 1) * 32;
      stage128x32(Whi, r0, NC, k1, Wh[nb], tid);
      stage128x32(xThi, xrow, NC, k1, Xh[nb], tid);
    }
    const int cur = ki & 1;

    short8 ah[4], bh[4];
#pragma unroll
    for (int i = 0; i < 4; ++i)
      ah[i] = *(short8*)&Xh[cur][(wa + i * 16 + l16) * 32 + quad * 8];
#pragma unroll
    for (int j = 0; j < 4; ++j)
      bh[j] = *(short8*)&Wh[cur][(wb + j * 16 + l16) * 32 + quad * 8];
#pragma unroll
    for (int i = 0; i < 4; ++i)
#pragma unroll
      for (int j = 0; j < 4; ++j)
        acc[i][j] = __builtin_amdgcn_mfma_f32_16x16x32_bf16(ah[i], bh[j], acc[i][j], 0, 0, 0);
  }

#pragma unroll
  for (int i = 0; i < 4; ++i)
#pragma unroll
    for (int j = 0; j < 4; ++j) {
      int nb = n0 + wa + i * 16 + quad * 4;
      int c  = r0 - 128 + wb + j * 16 + l16;
      ushort4 hi;
      hi.x = f32_to_bf16(acc[i][j][0]); hi.y = f32_to_bf16(acc[i][j][1]);
      hi.z = f32_to_bf16(acc[i][j][2]); hi.w = f32_to_bf16(acc[i][j][3]);
      *(ushort4*)&hw[((size_t)b * NC + c) * NN + nb] = hi;
    }
}

// ---------------------------------------------------------------------------
// Fused scores+softmax+PV+epilogue (flash-style; E never materialized).
// Exact R6/R11 structure (verified 81.0/79.4/77.5 us) + R12: s_setprio(1)
// around the S and PV MFMA clusters (T5 — the two co-resident blocks run at
// independent phases, so the MFMA-phase block wins issue slots over the
// staging/exp-phase block).
// ---------------------------------------------------------------------------
__global__ __launch_bounds__(512, 4)
void attn_out_kernel(const u16* __restrict__ fgThi, const u16* __restrict__ fgTlo,
                     const u16* __restrict__ hw, const float* __restrict__ x,
                     const float* __restrict__ gamma, float* __restrict__ out) {
  // XCD pinning: the 32 mt-blocks sharing one (b,ch) hw-panel land on one XCD.
  const int s = blockIdx.x;            // 0..511
  const int xcd = s & 7;
  const int t = s >> 3;                // 0..63
  const int mt = t & 31;               // m-tile 0..31
  const int hi6 = t >> 5;              // 0..1
  const int combo = (hi6 << 3) | xcd;  // 0..15 = (b,ch), bijective
  const int b = combo >> 1;
  const int ch = combo & 1;
  const int m0 = mt * 64;
  const int c0 = ch * 256;

  __shared__ u16 Fh[2][64 * 64], Fl[2][64 * 64];   // f [n][ch] 8 KB each
  __shared__ u16 Hs[256 * 64];                     // h [c][n] 32 KB single
  __shared__ u16 Ps[64 * 64];                      // P [m][n] 8 KB (Dn overlay)
  float* Dn = (float*)Ps;                          // valid after final PV

  const int tid = threadIdx.x, wave = tid >> 6, lane = tid & 63;
  const int quad = lane >> 4, l16 = lane & 15;
  const int ws_n = (wave >> 2) * 32, ws_m = (wave & 3) * 16;   // S partition
  const int wv_c = (wave >> 1) * 64, wv_m = (wave & 1) * 32;   // PV partition

  const size_t frow = (size_t)b * NN;
  const size_t hrow = (size_t)b * NC + c0;

  // g fragments -> registers (iter-invariant; cols 64..127 of fgT)
  short8 gh[2], gl[2];
#pragma unroll
  for (int k = 0; k < 2; ++k) {
    size_t o = (frow + m0 + ws_m + l16) * 128 + 64 + k * 32 + quad * 8;
    gh[k] = *(const short8*)&fgThi[o];
    gl[k] = *(const short8*)&fgTlo[o];
  }

  // prologue: stage F[0] (2 loads/thread) and H[0] (4 loads/thread)
  {
    int flat = tid * 16;
    int row = flat >> 7, chunk = (flat >> 4) & 7;
    int kb = ((chunk ^ (row & 7)) << 4);
    gl_lds16((const char*)(fgThi + (frow + row) * 128) + kb, Fh[0] + (tid & ~63) * 8);
    gl_lds16((const char*)(fgTlo + (frow + row) * 128) + kb, Fl[0] + (tid & ~63) * 8);
#pragma unroll
    for (int s2 = 0; s2 < 4; ++s2) {
      int f2 = s2 * 8192 + tid * 16;
      int r2 = f2 >> 7, c2 = (f2 >> 4) & 7;
      gl_lds16((const char*)(hw + (hrow + r2) * NN) + ((c2 ^ (r2 & 7)) << 4),
               Hs + s2 * 4096 + (tid & ~63) * 8);
    }
  }
  __syncthreads();   // F[0], H[0] landed

  float dsum = 0.f;
  f32x4 ao[4][2];
#pragma unroll
  for (int i = 0; i < 4; ++i)
#pragma unroll
    for (int j = 0; j < 2; ++j) ao[i][j] = (f32x4){0.f, 0.f, 0.f, 0.f};

  const int NT = NN / 64;   // 32
  for (int it = 0; it < NT; ++it) {
    const int cur = it & 1;

    // issue H[it] (skip it=0: prologue did it).  H buffer was freed by the
    // previous iter's trailing __syncthreads.
    if (it > 0) {
      const int n1 = it * 64;
#pragma unroll
      for (int s2 = 0; s2 < 4; ++s2) {
        int f2 = s2 * 8192 + tid * 16;
        int r2 = f2 >> 7, c2 = (f2 >> 4) & 7;
        gl_lds16((const char*)(hw + (hrow + r2) * NN + n1) + ((c2 ^ (r2 & 7)) << 4),
                 Hs + s2 * 4096 + (tid & ~63) * 8);
      }
    }
    // issue F[it+1]
    if (it + 1 < NT) {
      const int n1 = (it + 1) * 64;
      int flat = tid * 16;
      int row = flat >> 7, chunk = (flat >> 4) & 7;
      int kb = ((chunk ^ (row & 7)) << 4);
      gl_lds16((const char*)(fgThi + (frow + n1 + row) * 128) + kb,
               Fh[cur ^ 1] + (tid & ~63) * 8);
      gl_lds16((const char*)(fgTlo + (frow + n1 + row) * 128) + kb,
               Fl[cur ^ 1] + (tid & ~63) * 8);
    }

    // ---- S[it]: S[n64 x m64], 3-term split, g from registers ----
    f32x4 as[2];
#pragma unroll
    for (int i = 0; i < 2; ++i) as[i] = (f32x4){0.f, 0.f, 0.f, 0.f};
    __builtin_amdgcn_s_setprio(1);
#pragma unroll
    for (int k = 0; k < 2; ++k) {
      short8 fh[2], fl[2];
#pragma unroll
      for (int i = 0; i < 2; ++i) {
        int rr = ws_n + i * 16 + l16;
        int ci = (((k * 4 + quad) ^ (rr & 7)) << 3);
        fh[i] = *(short8*)&Fh[cur][rr * 64 + ci];
        fl[i] = *(short8*)&Fl[cur][rr * 64 + ci];
      }
#pragma unroll
      for (int i = 0; i < 2; ++i) {
        as[i] = __builtin_amdgcn_mfma_f32_16x16x32_bf16(fh[i], gh[k], as[i], 0, 0, 0);
        as[i] = __builtin_amdgcn_mfma_f32_16x16x32_bf16(fh[i], gl[k], as[i], 0, 0, 0);
        as[i] = __builtin_amdgcn_mfma_f32_16x16x32_bf16(fl[i], gh[k], as[i], 0, 0, 0);
      }
    }
    __builtin_amdgcn_s_setprio(0);

    // exp + P write (bf16, swizzled [m][n]) + denom partials
    {
      int m = ws_m + l16;
#pragma unroll
      for (int i = 0; i < 2; ++i) {
        float e0 = __expf(as[i][0]);
        float e1 = __expf(as[i][1]);
        float e2 = __expf(as[i][2]);
        float e3 = __expf(as[i][3]);
        dsum += (e0 + e1) + (e2 + e3);
        ushort4 pk;
        pk.x = f32_to_bf16(e0); pk.y = f32_to_bf16(e1);
        pk.z = f32_to_bf16(e2); pk.w = f32_to_bf16(e3);
        int nb = ws_n * 2 + i * 32 + quad * 8;      // byte offset in row
        int chunk = nb >> 4;
        int off = (nb & 15) >> 1;                   // u16 offset in chunk
        *(ushort4*)&Ps[m * 64 + ((chunk ^ (m & 7)) << 3) + off] = pk;
      }
    }

    // mid barrier: H[it] landed (counted vmcnt keeps F[it+1] in flight);
    // P visible via lgkm drain + barrier.
    if (it + 1 < NT) asm volatile("s_waitcnt vmcnt(2)" ::: "memory");
    else             asm volatile("s_waitcnt vmcnt(0)" ::: "memory");
    asm volatile("s_waitcnt lgkmcnt(0)" ::: "memory");
    __builtin_amdgcn_s_barrier();

    // ---- PV[it]: ao[c256 x m64] += h x P ----
    __builtin_amdgcn_s_setprio(1);
#pragma unroll
    for (int k = 0; k < 2; ++k) {
      short8 hh[4], pb[2];
#pragma unroll
      for (int i = 0; i < 4; ++i) {
        int rr = wv_c + i * 16 + l16;
        hh[i] = *(short8*)&Hs[rr * 64 + ((((k * 4 + quad)) ^ (rr & 7)) << 3)];
      }
#pragma unroll
      for (int j = 0; j < 2; ++j) {
        int rm = wv_m + j * 16 + l16;
        pb[j] = *(short8*)&Ps[rm * 64 + ((((k * 4 + quad)) ^ (rm & 7)) << 3)];
      }
#pragma unroll
      for (int i = 0; i < 4; ++i)
#pragma unroll
        for (int j = 0; j < 2; ++j)
          ao[i][j] = __builtin_amdgcn_mfma_f32_16x16x32_bf16(hh[i], pb[j], ao[i][j], 0, 0, 0);
    }
    __builtin_amdgcn_s_setprio(0);

    // iter-end: PV reads done -> H/P buffers free; drains F[it+1] (issued a
    // full phase ago) so next S can read it.
    __syncthreads();
  }

  // ---- epilogue: denom reduce (deterministic, in-block; Dn overlays Ps) ----
  dsum += __shfl_xor(dsum, 16);
  dsum += __shfl_xor(dsum, 32);
  if (tid < 64) Dn[tid] = 0.f;
  __syncthreads();
  if (quad == 0) atomicAdd(&Dn[ws_m + l16], dsum);
  __syncthreads();

  const float g = gamma[0];
  float invd[2];
#pragma unroll
  for (int j = 0; j < 2; ++j)
    invd[j] = g / Dn[wv_m + j * 16 + l16];

#pragma unroll
  for (int i = 0; i < 4; ++i) {
#pragma unroll
    for (int j = 0; j < 2; ++j) {
      const int c = c0 + wv_c + i * 16 + quad * 4;
      const int m = m0 + wv_m + j * 16 + l16;
#pragma unroll
      for (int r = 0; r < 4; ++r) {
        size_t off = ((size_t)b * NC + c + r) * NN + m;
        out[off] = fmaf(invd[j], ao[i][j][r], x[off]);
      }
    }
  }
}

// ---------------------------------------------------------------------------
extern "C" void kernel_launch(void* const* d_in, const int* in_sizes, int n_in,
                              void* d_out, int out_size, void* d_ws, size_t ws_size,
                              hipStream_t stream) {
  const float* x     = (const float*)d_in[0];
  const float* Wq    = (const float*)d_in[1];
  const float* Wk    = (const float*)d_in[2];
  const float* Wv    = (const float*)d_in[3];
  const float* gamma = (const float*)d_in[4];
  float* out = (float*)d_out;

  // Workspace (R6 layout):
  //   [0          ) xThi bf16 [8][2048][512]   16,777,216
  //   [16,777,216 ) xTlo                        16,777,216
  //   [33,554,432 ) Whi  bf16 [640][512]           655,360
  //   [34,209,792 ) Wlo                            655,360
  //   [67,108,864 ) fgThi bf16 [8][2048][128]    4,194,304
  //   [71,303,168 ) fgTlo                        4,194,304
  //   [75,497,472 ) hw    bf16 [8][512][2048]   16,777,216
  char* ws = (char*)d_ws;
  u16*   xThi  = (u16*)ws;
  u16*   xTlo  = (u16*)(ws + 16777216);
  u16*   Whi   = (u16*)(ws + 33554432);
  u16*   Wlo   = (u16*)(ws + 34209792);
  u16*   fgThi = (u16*)(ws + 67108864);
  u16*   fgTlo = (u16*)(ws + 71303168);
  u16*   hw    = (u16*)(ws + 75497472);

  xsplit_kernel<<<dim3(NN / 64, NC / 64, NB), 256, 0, stream>>>(
      x, Wq, Wk, Wv, xThi, xTlo, Whi, Wlo);
  proj_fg_kernel<<<dim3(NN / 128, 2, NB), 256, 0, stream>>>(
      xThi, xTlo, Whi, Wlo, fgThi, fgTlo);
  proj_h_kernel<<<dim3(NN / 128, 4, NB), 256, 0, stream>>>(xThi, Whi, hw);
  attn_out_kernel<<<dim3(512), 512, 0, stream>>>(fgThi, fgTlo, hw, x, gamma, out);
}

// Round 15
// 189.417 us; speedup vs baseline: 1.3988x; 1.0095x over previous
//
#include <hip/hip_runtime.h>
#include <hip/hip_bf16.h>
#include <math.h>

// Problem dims (fixed by the reference)
#define NB 8
#define NC 512
#define NN 2048

typedef unsigned short u16;
typedef __attribute__((ext_vector_type(8))) short short8;
typedef __attribute__((ext_vector_type(4))) float f32x4;

__device__ __forceinline__ float bf16_to_f32(u16 v) {
  union { unsigned int u; float f; } c; c.u = ((unsigned int)v) << 16; return c.f;
}
__device__ __forceinline__ u16 f32_to_bf16(float f) {
  __hip_bfloat16 h = __float2bfloat16(f);   // RNE
  union { __hip_bfloat16 h; u16 u; } c; c.h = h; return c.u;
}
__device__ __forceinline__ void split2(float v, unsigned short& hi, unsigned short& lo) {
  hi = f32_to_bf16(v);
  lo = f32_to_bf16(v - bf16_to_f32(hi));
}

__device__ __forceinline__ void gl_lds16(const void* g, void* l) {
  __builtin_amdgcn_global_load_lds(
      (const __attribute__((address_space(1))) unsigned int*)g,
      (__attribute__((address_space(3))) unsigned int*)l, 16, 0, 0);
}

// stage 128 rows x 32 u16 (64 B/row, 8 KB) into LDS via global_load_lds w=16.
__device__ __forceinline__ void stage128x32(const u16* __restrict__ src, size_t row_base,
                                            int selems, int k0, u16* lds, int tid) {
#pragma unroll
  for (int s = 0; s < 2; ++s) {
    int flat = s * 4096 + tid * 16;   // byte offset within tile
    int row = flat >> 6;
    int kb  = flat & 63;
    const char* g = (const char*)(src + (row_base + row) * (size_t)selems + k0) + kb;
    u16* l = lds + s * 2048 + (tid & ~63) * 8;  // wave-uniform base; HW adds lane*16
    gl_lds16(g, l);
  }
}

// stage 64 rows x 32 u16 (64 B/row, 4 KB): 1 load/thread at 256 threads.
__device__ __forceinline__ void stage64x32(const u16* __restrict__ src, size_t row_base,
                                           int selems, int k0, u16* lds, int tid) {
  int flat = tid * 16;
  int row = flat >> 6;
  int kb  = flat & 63;
  const char* g = (const char*)(src + (row_base + row) * (size_t)selems + k0) + kb;
  gl_lds16(g, lds + (tid & ~63) * 8);
}

// ---------------------------------------------------------------------------
// x transpose + split: x[b][c][n] fp32 -> xThi/xTlo[b][n][c] bf16.
// wsplit folded in (R11, verified): first 320 flat blocks also convert one
// 1024-elem chunk of [Wq;Wk;Wv] -> Whi/Wlo.  (Byte-identical to R14.)
// ---------------------------------------------------------------------------
__global__ __launch_bounds__(256)
void xsplit_kernel(const float* __restrict__ x,
                   const float* __restrict__ Wq, const float* __restrict__ Wk,
                   const float* __restrict__ Wv,
                   u16* __restrict__ xThi, u16* __restrict__ xTlo,
                   u16* __restrict__ Whi, u16* __restrict__ Wlo) {
  const int b = blockIdx.z, c0 = blockIdx.y * 64, n0 = blockIdx.x * 64;
  const int tid = threadIdx.x;

  // --- merged W split (first 320 flat blocks; no LDS, before any barrier) ---
  int fid = blockIdx.x + 32 * (blockIdx.y + 8 * blockIdx.z);
  if (fid < 320) {
    int idx = (fid * 256 + tid) * 4;   // 640*512 total, exact
    int r = idx >> 9, c = idx & 511;
    const float* src;
    if (r < 64)       src = Wq + (size_t)r * NC + c;
    else if (r < 128) src = Wk + (size_t)(r - 64) * NC + c;
    else              src = Wv + (size_t)(r - 128) * NC + c;
    float4 v = *(const float4*)src;
    ushort4 hi, lo;
    split2(v.x, hi.x, lo.x); split2(v.y, hi.y, lo.y);
    split2(v.z, hi.z, lo.z); split2(v.w, hi.w, lo.w);
    *(ushort4*)&Whi[idx] = hi;
    *(ushort4*)&Wlo[idx] = lo;
  }

  __shared__ float t[64][65];
  const int tx = tid & 15, ty = tid >> 4;
#pragma unroll
  for (int r = 0; r < 4; ++r) {
    int c = r * 16 + ty;
    float4 v = *(const float4*)&x[((size_t)b * NC + c0 + c) * NN + n0 + tx * 4];
    t[c][tx * 4 + 0] = v.x; t[c][tx * 4 + 1] = v.y;
    t[c][tx * 4 + 2] = v.z; t[c][tx * 4 + 3] = v.w;
  }
  __syncthreads();
#pragma unroll
  for (int r = 0; r < 4; ++r) {
    int n = r * 16 + ty;
    ushort4 hi, lo;
    split2(t[tx * 4 + 0][n], hi.x, lo.x);
    split2(t[tx * 4 + 1][n], hi.y, lo.y);
    split2(t[tx * 4 + 2][n], hi.z, lo.z);
    split2(t[tx * 4 + 3][n], hi.w, lo.w);
    size_t off = ((size_t)b * NN + n0 + n) * NC + c0 + tx * 4;
    *(ushort4*)&xThi[off] = hi;
    *(ushort4*)&xTlo[off] = lo;
  }
}

// ---------------------------------------------------------------------------
// proj_fg: rows 0..127 = [f;g] -> fgT[b][n][128], 3-term split product.
// R15 re-tile: 64r x 64n per block -> 512 blocks = exactly 2/CU (the R12
// 64x128 shape was 256 blocks = 1 block/CU = 1 wave/SIMD: zero latency
// hiding).  LDS 32 KB (4 arrays x 2 buf x 4 KB).  W staged per-n-block
// (1.3 MB total traffic - noise).  12 MFMA/wave/iter (acc[2][2] x 3 terms).
// ---------------------------------------------------------------------------
__global__ __launch_bounds__(256)
void proj_fg_kernel(const u16* __restrict__ xThi, const u16* __restrict__ xTlo,
                    const u16* __restrict__ Whi, const u16* __restrict__ Wlo,
                    u16* __restrict__ fgThi, u16* __restrict__ fgTlo) {
  const int b  = blockIdx.z;
  const int n0 = blockIdx.x * 64;
  const int r0 = blockIdx.y * 64;     // 0 (f) or 64 (g)

  __shared__ u16 Wh[2][64 * 32], Wl[2][64 * 32], Xh[2][64 * 32], Xl[2][64 * 32];

  const int tid = threadIdx.x, wave = tid >> 6, lane = tid & 63;
  const int quad = lane >> 4, l16 = lane & 15;
  const int wa = (wave >> 1) * 32, wb = (wave & 1) * 32;
  const size_t xrow = (size_t)b * NN + n0;

  f32x4 acc[2][2];
#pragma unroll
  for (int i = 0; i < 2; ++i)
#pragma unroll
    for (int j = 0; j < 2; ++j) acc[i][j] = (f32x4){0.f, 0.f, 0.f, 0.f};

  // prologue: stage k=0 into buf 0
  stage64x32(Whi, r0, NC, 0, Wh[0], tid);
  stage64x32(Wlo, r0, NC, 0, Wl[0], tid);
  stage64x32(xThi, xrow, NC, 0, Xh[0], tid);
  stage64x32(xTlo, xrow, NC, 0, Xl[0], tid);

  const int KIT = NC / 32;   // 16
  for (int ki = 0; ki < KIT; ++ki) {
    __syncthreads();
    if (ki + 1 < KIT) {
      const int nb = (ki + 1) & 1, k1 = (ki + 1) * 32;
      stage64x32(Whi, r0, NC, k1, Wh[nb], tid);
      stage64x32(Wlo, r0, NC, k1, Wl[nb], tid);
      stage64x32(xThi, xrow, NC, k1, Xh[nb], tid);
      stage64x32(xTlo, xrow, NC, k1, Xl[nb], tid);
    }
    const int cur = ki & 1;

    short8 ah[2], al[2], bh[2], bl[2];
#pragma unroll
    for (int i = 0; i < 2; ++i) {
      ah[i] = *(short8*)&Wh[cur][(wa + i * 16 + l16) * 32 + quad * 8];
      al[i] = *(short8*)&Wl[cur][(wa + i * 16 + l16) * 32 + quad * 8];
    }
#pragma unroll
    for (int j = 0; j < 2; ++j) {
      bh[j] = *(short8*)&Xh[cur][(wb + j * 16 + l16) * 32 + quad * 8];
      bl[j] = *(short8*)&Xl[cur][(wb + j * 16 + l16) * 32 + quad * 8];
    }
#pragma unroll
    for (int i = 0; i < 2; ++i)
#pragma unroll
      for (int j = 0; j < 2; ++j) {
        acc[i][j] = __builtin_amdgcn_mfma_f32_16x16x32_bf16(ah[i], bh[j], acc[i][j], 0, 0, 0);
        acc[i][j] = __builtin_amdgcn_mfma_f32_16x16x32_bf16(ah[i], bl[j], acc[i][j], 0, 0, 0);
        acc[i][j] = __builtin_amdgcn_mfma_f32_16x16x32_bf16(al[i], bh[j], acc[i][j], 0, 0, 0);
      }
  }

#pragma unroll
  for (int i = 0; i < 2; ++i)
#pragma unroll
    for (int j = 0; j < 2; ++j) {
      int rb = r0 + wa + i * 16 + quad * 4;
      int n  = n0 + wb + j * 16 + l16;
      ushort4 hi, lo;
      split2(acc[i][j][0], hi.x, lo.x); split2(acc[i][j][1], hi.y, lo.y);
      split2(acc[i][j][2], hi.z, lo.z); split2(acc[i][j][3], hi.w, lo.w);
      size_t off = ((size_t)b * NN + n) * 128 + rb;
      *(ushort4*)&fgThi[off] = hi;
      *(ushort4*)&fgTlo[off] = lo;
    }
}

// ---------------------------------------------------------------------------
// proj_h: rows 128..639 = h -> hw[b][c][n] bf16 (single-term hi*hi).
// R15: BK=64 via two stacked 32-col sub-tiles per buffer (same verified
// 64 B-row layout/bank behavior; staged by two stage128x32 calls at k and
// k+32).  Barriers halve (16 -> 8 iters), 32 MFMA/wave per phase.  LDS
// 64 KB -> still 2 blocks/CU (128 KB < 160).
// ---------------------------------------------------------------------------
__global__ __launch_bounds__(256)
void proj_h_kernel(const u16* __restrict__ xThi, const u16* __restrict__ Whi,
                   u16* __restrict__ hw) {
  const int b  = blockIdx.z;
  const int n0 = blockIdx.x * 128;
  const int r0 = 128 + blockIdx.y * 128;

  __shared__ u16 Wh[2][2 * 128 * 32], Xh[2][2 * 128 * 32];

  const int tid = threadIdx.x, wave = tid >> 6, lane = tid & 63;
  const int quad = lane >> 4, l16 = lane & 15;
  const int wa = (wave >> 1) * 64, wb = (wave & 1) * 64;
  const size_t xrow = (size_t)b * NN + n0;

  f32x4 acc[4][4];
#pragma unroll
  for (int i = 0; i < 4; ++i)
#pragma unroll
    for (int j = 0; j < 4; ++j) acc[i][j] = (f32x4){0.f, 0.f, 0.f, 0.f};

  // prologue: stage k=0..63 into buf 0 (two 32-col halves)
  stage128x32(Whi, r0, NC, 0,  Wh[0], tid);
  stage128x32(Whi, r0, NC, 32, Wh[0] + 4096, tid);
  stage128x32(xThi, xrow, NC, 0,  Xh[0], tid);
  stage128x32(xThi, xrow, NC, 32, Xh[0] + 4096, tid);

  const int KIT = NC / 64;   // 8
  for (int ki = 0; ki < KIT; ++ki) {
    __syncthreads();
    if (ki + 1 < KIT) {
      const int nb = (ki + 1) & 1, k1 = (ki + 1) * 64;
      stage128x32(Whi, r0, NC, k1,      Wh[nb], tid);
      stage128x32(Whi, r0, NC, k1 + 32, Wh[nb] + 4096, tid);
      stage128x32(xThi, xrow, NC, k1,      Xh[nb], tid);
      stage128x32(xThi, xrow, NC, k1 + 32, Xh[nb] + 4096, tid);
    }
    const int cur = ki & 1;

#pragma unroll
    for (int ks = 0; ks < 2; ++ks) {
      const int base = ks * 4096;
      short8 ah[4], bh[4];
#pragma unroll
      for (int i = 0; i < 4; ++i)
        ah[i] = *(short8*)&Xh[cur][base + (wa + i * 16 + l16) * 32 + quad * 8];
#pragma unroll
      for (int j = 0; j < 4; ++j)
        bh[j] = *(short8*)&Wh[cur][base + (wb + j * 16 + l16) * 32 + quad * 8];
#pragma unroll
      for (int i = 0; i < 4; ++i)
#pragma unroll
        for (int j = 0; j < 4; ++j)
          acc[i][j] = __builtin_amdgcn_mfma_f32_16x16x32_bf16(ah[i], bh[j], acc[i][j], 0, 0, 0);
    }
  }

#pragma unroll
  for (int i = 0; i < 4; ++i)
#pragma unroll
    for (int j = 0; j < 4; ++j) {
      int nb = n0 + wa + i * 16 + quad * 4;
      int c  = r0 - 128 + wb + j * 16 + l16;
      ushort4 hi;
      hi.x = f32_to_bf16(acc[i][j][0]); hi.y = f32_to_bf16(acc[i][j][1]);
      hi.z = f32_to_bf16(acc[i][j][2]); hi.w = f32_to_bf16(acc[i][j][3]);
      *(ushort4*)&hw[((size_t)b * NC + c) * NN + nb] = hi;
    }
}

// ---------------------------------------------------------------------------
// Fused scores+softmax+PV+epilogue (flash-style; E never materialized).
// Byte-identical to R14's verified kernel (74.5-74.7 us): R6 structure +
// s_setprio(1) around the S and PV MFMA clusters (T5).
// ---------------------------------------------------------------------------
__global__ __launch_bounds__(512, 4)
void attn_out_kernel(const u16* __restrict__ fgThi, const u16* __restrict__ fgTlo,
                     const u16* __restrict__ hw, const float* __restrict__ x,
                     const float* __restrict__ gamma, float* __restrict__ out) {
  // XCD pinning: the 32 mt-blocks sharing one (b,ch) hw-panel land on one XCD.
  const int s = blockIdx.x;            // 0..511
  const int xcd = s & 7;
  const int t = s >> 3;                // 0..63
  const int mt = t & 31;               // m-tile 0..31
  const int hi6 = t >> 5;              // 0..1
  const int combo = (hi6 << 3) | xcd;  // 0..15 = (b,ch), bijective
  const int b = combo >> 1;
  const int ch = combo & 1;
  const int m0 = mt * 64;
  const int c0 = ch * 256;

  __shared__ u16 Fh[2][64 * 64], Fl[2][64 * 64];   // f [n][ch] 8 KB each
  __shared__ u16 Hs[256 * 64];                     // h [c][n] 32 KB single
  __shared__ u16 Ps[64 * 64];                      // P [m][n] 8 KB (Dn overlay)
  float* Dn = (float*)Ps;                          // valid after final PV

  const int tid = threadIdx.x, wave = tid >> 6, lane = tid & 63;
  const int quad = lane >> 4, l16 = lane & 15;
  const int ws_n = (wave >> 2) * 32, ws_m = (wave & 3) * 16;   // S partition
  const int wv_c = (wave >> 1) * 64, wv_m = (wave & 1) * 32;   // PV partition

  const size_t frow = (size_t)b * NN;
  const size_t hrow = (size_t)b * NC + c0;

  // g fragments -> registers (iter-invariant; cols 64..127 of fgT)
  short8 gh[2], gl[2];
#pragma unroll
  for (int k = 0; k < 2; ++k) {
    size_t o = (frow + m0 + ws_m + l16) * 128 + 64 + k * 32 + quad * 8;
    gh[k] = *(const short8*)&fgThi[o];
    gl[k] = *(const short8*)&fgTlo[o];
  }

  // prologue: stage F[0] (2 loads/thread) and H[0] (4 loads/thread)
  {
    int flat = tid * 16;
    int row = flat >> 7, chunk = (flat >> 4) & 7;
    int kb = ((chunk ^ (row & 7)) << 4);
    gl_lds16((const char*)(fgThi + (frow + row) * 128) + kb, Fh[0] + (tid & ~63) * 8);
    gl_lds16((const char*)(fgTlo + (frow + row) * 128) + kb, Fl[0] + (tid & ~63) * 8);
#pragma unroll
    for (int s2 = 0; s2 < 4; ++s2) {
      int f2 = s2 * 8192 + tid * 16;
      int r2 = f2 >> 7, c2 = (f2 >> 4) & 7;
      gl_lds16((const char*)(hw + (hrow + r2) * NN) + ((c2 ^ (r2 & 7)) << 4),
               Hs + s2 * 4096 + (tid & ~63) * 8);
    }
  }
  __syncthreads();   // F[0], H[0] landed

  float dsum = 0.f;
  f32x4 ao[4][2];
#pragma unroll
  for (int i = 0; i < 4; ++i)
#pragma unroll
    for (int j = 0; j < 2; ++j) ao[i][j] = (f32x4){0.f, 0.f, 0.f, 0.f};

  const int NT = NN / 64;   // 32
  for (int it = 0; it < NT; ++it) {
    const int cur = it & 1;

    // issue H[it] (skip it=0: prologue did it).  H buffer was freed by the
    // previous iter's trailing __syncthreads.
    if (it > 0) {
      const int n1 = it * 64;
#pragma unroll
      for (int s2 = 0; s2 < 4; ++s2) {
        int f2 = s2 * 8192 + tid * 16;
        int r2 = f2 >> 7, c2 = (f2 >> 4) & 7;
        gl_lds16((const char*)(hw + (hrow + r2) * NN + n1) + ((c2 ^ (r2 & 7)) << 4),
                 Hs + s2 * 4096 + (tid & ~63) * 8);
      }
    }
    // issue F[it+1]
    if (it + 1 < NT) {
      const int n1 = (it + 1) * 64;
      int flat = tid * 16;
      int row = flat >> 7, chunk = (flat >> 4) & 7;
      int kb = ((chunk ^ (row & 7)) << 4);
      gl_lds16((const char*)(fgThi + (frow + n1 + row) * 128) + kb,
               Fh[cur ^ 1] + (tid & ~63) * 8);
      gl_lds16((const char*)(fgTlo + (frow + n1 + row) * 128) + kb,
               Fl[cur ^ 1] + (tid & ~63) * 8);
    }

    // ---- S[it]: S[n64 x m64], 3-term split, g from registers ----
    f32x4 as[2];
#pragma unroll
    for (int i = 0; i < 2; ++i) as[i] = (f32x4){0.f, 0.f, 0.f, 0.f};
    __builtin_amdgcn_s_setprio(1);
#pragma unroll
    for (int k = 0; k < 2; ++k) {
      short8 fh[2], fl[2];
#pragma unroll
      for (int i = 0; i < 2; ++i) {
        int rr = ws_n + i * 16 + l16;
        int ci = (((k * 4 + quad) ^ (rr & 7)) << 3);
        fh[i] = *(short8*)&Fh[cur][rr * 64 + ci];
        fl[i] = *(short8*)&Fl[cur][rr * 64 + ci];
      }
#pragma unroll
      for (int i = 0; i < 2; ++i) {
        as[i] = __builtin_amdgcn_mfma_f32_16x16x32_bf16(fh[i], gh[k], as[i], 0, 0, 0);
        as[i] = __builtin_amdgcn_mfma_f32_16x16x32_bf16(fh[i], gl[k], as[i], 0, 0, 0);
        as[i] = __builtin_amdgcn_mfma_f32_16x16x32_bf16(fl[i], gh[k], as[i], 0, 0, 0);
      }
    }
    __builtin_amdgcn_s_setprio(0);

    // exp + P write (bf16, swizzled [m][n]) + denom partials
    {
      int m = ws_m + l16;
#pragma unroll
      for (int i = 0; i < 2; ++i) {
        float e0 = __expf(as[i][0]);
        float e1 = __expf(as[i][1]);
        float e2 = __expf(as[i][2]);
        float e3 = __expf(as[i][3]);
        dsum += (e0 + e1) + (e2 + e3);
        ushort4 pk;
        pk.x = f32_to_bf16(e0); pk.y = f32_to_bf16(e1);
        pk.z = f32_to_bf16(e2); pk.w = f32_to_bf16(e3);
        int nb = ws_n * 2 + i * 32 + quad * 8;      // byte offset in row
        int chunk = nb >> 4;
        int off = (nb & 15) >> 1;                   // u16 offset in chunk
        *(ushort4*)&Ps[m * 64 + ((chunk ^ (m & 7)) << 3) + off] = pk;
      }
    }

    // mid barrier: H[it] landed (counted vmcnt keeps F[it+1] in flight);
    // P visible via lgkm drain + barrier.
    if (it + 1 < NT) asm volatile("s_waitcnt vmcnt(2)" ::: "memory");
    else             asm volatile("s_waitcnt vmcnt(0)" ::: "memory");
    asm volatile("s_waitcnt lgkmcnt(0)" ::: "memory");
    __builtin_amdgcn_s_barrier();

    // ---- PV[it]: ao[c256 x m64] += h x P ----
    __builtin_amdgcn_s_setprio(1);
#pragma unroll
    for (int k = 0; k < 2; ++k) {
      short8 hh[4], pb[2];
#pragma unroll
      for (int i = 0; i < 4; ++i) {
        int rr = wv_c + i * 16 + l16;
        hh[i] = *(short8*)&Hs[rr * 64 + ((((k * 4 + quad)) ^ (rr & 7)) << 3)];
      }
#pragma unroll
      for (int j = 0; j < 2; ++j) {
        int rm = wv_m + j * 16 + l16;
        pb[j] = *(short8*)&Ps[rm * 64 + ((((k * 4 + quad)) ^ (rm & 7)) << 3)];
      }
#pragma unroll
      for (int i = 0; i < 4; ++i)
#pragma unroll
        for (int j = 0; j < 2; ++j)
          ao[i][j] = __builtin_amdgcn_mfma_f32_16x16x32_bf16(hh[i], pb[j], ao[i][j], 0, 0, 0);
    }
    __builtin_amdgcn_s_setprio(0);

    // iter-end: PV reads done -> H/P buffers free; drains F[it+1] (issued a
    // full phase ago) so next S can read it.
    __syncthreads();
  }

  // ---- epilogue: denom reduce (deterministic, in-block; Dn overlays Ps) ----
  dsum += __shfl_xor(dsum, 16);
  dsum += __shfl_xor(dsum, 32);
  if (tid < 64) Dn[tid] = 0.f;
  __syncthreads();
  if (quad == 0) atomicAdd(&Dn[ws_m + l16], dsum);
  __syncthreads();

  const float g = gamma[0];
  float invd[2];
#pragma unroll
  for (int j = 0; j < 2; ++j)
    invd[j] = g / Dn[wv_m + j * 16 + l16];

#pragma unroll
  for (int i = 0; i < 4; ++i) {
#pragma unroll
    for (int j = 0; j < 2; ++j) {
      const int c = c0 + wv_c + i * 16 + quad * 4;
      const int m = m0 + wv_m + j * 16 + l16;
#pragma unroll
      for (int r = 0; r < 4; ++r) {
        size_t off = ((size_t)b * NC + c + r) * NN + m;
        out[off] = fmaf(invd[j], ao[i][j][r], x[off]);
      }
    }
  }
}

// ---------------------------------------------------------------------------
extern "C" void kernel_launch(void* const* d_in, const int* in_sizes, int n_in,
                              void* d_out, int out_size, void* d_ws, size_t ws_size,
                              hipStream_t stream) {
  const float* x     = (const float*)d_in[0];
  const float* Wq    = (const float*)d_in[1];
  const float* Wk    = (const float*)d_in[2];
  const float* Wv    = (const float*)d_in[3];
  const float* gamma = (const float*)d_in[4];
  float* out = (float*)d_out;

  // Workspace (R6 layout):
  //   [0          ) xThi bf16 [8][2048][512]   16,777,216
  //   [16,777,216 ) xTlo                        16,777,216
  //   [33,554,432 ) Whi  bf16 [640][512]           655,360
  //   [34,209,792 ) Wlo                            655,360
  //   [67,108,864 ) fgThi bf16 [8][2048][128]    4,194,304
  //   [71,303,168 ) fgTlo                        4,194,304
  //   [75,497,472 ) hw    bf16 [8][512][2048]   16,777,216
  char* ws = (char*)d_ws;
  u16*   xThi  = (u16*)ws;
  u16*   xTlo  = (u16*)(ws + 16777216);
  u16*   Whi   = (u16*)(ws + 33554432);
  u16*   Wlo   = (u16*)(ws + 34209792);
  u16*   fgThi = (u16*)(ws + 67108864);
  u16*   fgTlo = (u16*)(ws + 71303168);
  u16*   hw    = (u16*)(ws + 75497472);

  xsplit_kernel<<<dim3(NN / 64, NC / 64, NB), 256, 0, stream>>>(
      x, Wq, Wk, Wv, xThi, xTlo, Whi, Wlo);
  proj_fg_kernel<<<dim3(NN / 64, 2, NB), 256, 0, stream>>>(
      xThi, xTlo, Whi, Wlo, fgThi, fgTlo);
  proj_h_kernel<<<dim3(NN / 128, 4, NB), 256, 0, stream>>>(xThi, Whi, hw);
  attn_out_kernel<<<dim3(512), 512, 0, stream>>>(fgThi, fgTlo, hw, x, gamma, out);
}